// Round 3
// baseline (4547.171 us; speedup 1.0000x reference)
//
#include <hip/hip_runtime.h>
#include <hip/hip_bf16.h>
#include <math.h>

typedef __hip_bfloat16 bf16;

#define EMB 12
#define NCLS 17
#define NG 1000
#define BSHIFT 9
#define BSPAN 512            // cols per bucket
#define MAXNB 1024           // max buckets (N <= 524287)
#define CHUNK 16384          // edges per block in count/place
#define EB 8                 // edge batch (MLP) in count/place
#define TSHIFT 16            // source tile = 65536 nodes = 2 MB bf16 (fits 4MB XCD L2)
#define NTILE 8              // max tiles (N < 2^19)
#define NKEY (BSPAN*NTILE)   // 4096 sort keys in k_group
#define GGRID 1024           // persistent gather grid (4 blocks/CU x 256 CU)
#define GSTRIDE (GGRID*256)  // 262144 columns per sweep

__device__ __forceinline__ float b2f(bf16 v){ return __bfloat162float(v); }

__device__ __forceinline__ unsigned short f2bf_rne(float f){
  unsigned int u = __float_as_uint(f);
  unsigned int r = (u + 0x7FFFu + ((u >> 16) & 1u)) >> 16;
  return (unsigned short)r;
}

__device__ __forceinline__ float ldf(const void* p, size_t i, int isbf){
  if (isbf) return b2f(((const bf16*)p)[i]);
  return ((const float*)p)[i];
}
__device__ __forceinline__ void stout(void* p, size_t i, float v, int isbf){
  if (isbf) ((unsigned short*)p)[i] = f2bf_rne(v);
  else      ((float*)p)[i] = v;
}

// ---- row load/store, stride 16 elements ----------------------------------
__device__ __forceinline__ void rowload(const float* p, float o[12]){
  const float4* q = (const float4*)p;
  float4 a = q[0], b = q[1], c = q[2];
  o[0]=a.x;o[1]=a.y;o[2]=a.z;o[3]=a.w;o[4]=b.x;o[5]=b.y;o[6]=b.z;o[7]=b.w;
  o[8]=c.x;o[9]=c.y;o[10]=c.z;o[11]=c.w;
}
__device__ __forceinline__ void rowload(const bf16* p, float o[12]){
  const uint4* q = (const uint4*)p;       // 32B row, 16B aligned
  uint4 u0 = q[0];
  uint2 u1 = *(const uint2*)(q+1);
  o[0] =__uint_as_float(u0.x<<16); o[1] =__uint_as_float(u0.x&0xFFFF0000u);
  o[2] =__uint_as_float(u0.y<<16); o[3] =__uint_as_float(u0.y&0xFFFF0000u);
  o[4] =__uint_as_float(u0.z<<16); o[5] =__uint_as_float(u0.z&0xFFFF0000u);
  o[6] =__uint_as_float(u0.w<<16); o[7] =__uint_as_float(u0.w&0xFFFF0000u);
  o[8] =__uint_as_float(u1.x<<16); o[9] =__uint_as_float(u1.x&0xFFFF0000u);
  o[10]=__uint_as_float(u1.y<<16); o[11]=__uint_as_float(u1.y&0xFFFF0000u);
}
__device__ __forceinline__ void rowstore(float* p, const float o[12]){
  float4* q = (float4*)p;
  q[0] = make_float4(o[0],o[1],o[2],o[3]);
  q[1] = make_float4(o[4],o[5],o[6],o[7]);
  q[2] = make_float4(o[8],o[9],o[10],o[11]);
}
__device__ __forceinline__ void rowstore(bf16* p, const float o[12]){
  unsigned int u[6];
  #pragma unroll
  for (int k=0;k<6;k++)
    u[k] = (unsigned int)f2bf_rne(o[2*k]) | ((unsigned int)f2bf_rne(o[2*k+1])<<16);
  uint2* q = (uint2*)p;
  q[0] = make_uint2(u[0],u[1]);
  q[1] = make_uint2(u[2],u[3]);
  q[2] = make_uint2(u[4],u[5]);
}

// ---- runtime dtype detection ---------------------------------------------
__global__ void k_detect(const int* __restrict__ ei, const unsigned short* __restrict__ xh,
                         int* __restrict__ flags){
  if (blockIdx.x==0 && threadIdx.x==0){
    int z = 1;
    for (int k=1; k<32; k+=2) z &= (ei[k]==0);
    flags[0] = z;
    int hits = 0;
    for (int k=0; k<32; k+=2){
      int e = (xh[k] >> 7) & 0xFF;
      if (e >= 100 && e <= 140) hits++;
    }
    flags[1] = (hits >= 12) ? 1 : 0;
  }
}
__device__ __forceinline__ int ld_row(const int* ei, long long E, long long i, int w64){
  return w64 ? ei[2*i] : ei[i];
}
__device__ __forceinline__ int ld_col(const int* ei, long long E, long long i, int w64){
  return w64 ? ei[2*E + 2*i] : ei[E + i];
}
__device__ __forceinline__ int ld_batch(const int* b, long long i, int w64){
  return w64 ? b[2*i] : b[i];
}

// ---- grid phase barrier (locality-only; single-use slots; timeout-safe) --
__device__ __forceinline__ void gridbar(int* slot, int nb){
  __syncthreads();
  if (threadIdx.x == 0){
    __threadfence();
    int old = __hip_atomic_fetch_add(&slot[0], 1, __ATOMIC_ACQ_REL, __HIP_MEMORY_SCOPE_AGENT);
    if (old == nb-1){
      __hip_atomic_store(&slot[1], 1, __ATOMIC_RELEASE, __HIP_MEMORY_SCOPE_AGENT);
    } else {
      int it = 0;
      while (__hip_atomic_load(&slot[1], __ATOMIC_ACQUIRE, __HIP_MEMORY_SCOPE_AGENT) == 0
             && it < (1<<20)){
        __builtin_amdgcn_s_sleep(4);
        it++;
      }
    }
  }
  __syncthreads();
}

// ---- bucketed CSR build (no per-edge global atomics) ---------------------
__global__ void k_zero_i(int* __restrict__ p, int n){
  int i = blockIdx.x*blockDim.x + threadIdx.x;
  if (i < n) p[i] = 0;
}
// Pass A: per-block LDS histogram; writes per-block counts (bofs) + totals.
__global__ void __launch_bounds__(256)
k_bkt_count(const int* __restrict__ ei, const int* __restrict__ flags,
            int* __restrict__ bcnt, int* __restrict__ bofs, int E, int NB){
  __shared__ int h[MAXNB];
  int t = threadIdx.x;
  for (int j=t; j<NB; j+=256) h[j] = 0;
  __syncthreads();
  int w64 = flags[0];
  long long base = (long long)blockIdx.x * CHUNK;
  for (int k0=0; k0<CHUNK; k0+=256*EB){
    int c[EB]; bool v[EB];
    #pragma unroll
    for (int u=0;u<EB;u++){
      long long i = base + k0 + u*256 + t;
      v[u] = (i < E);
      c[u] = v[u] ? ld_col(ei, E, i, w64) : 0;
    }
    #pragma unroll
    for (int u=0;u<EB;u++) if (v[u]) atomicAdd(&h[c[u]>>BSHIFT], 1);
  }
  __syncthreads();
  size_t rowb = (size_t)blockIdx.x * NB;
  for (int j=t; j<NB; j+=256){
    int c = h[j];
    bofs[rowb + j] = c;
    if (c > 0) atomicAdd(&bcnt[j], c);
  }
}
// bucket-total scan (single block); also writes rs2 sentinel.
__global__ void __launch_bounds__(1024)
k_bkt_scan_par(const int* __restrict__ bcnt, int* __restrict__ bbase,
               int* __restrict__ rs2, int NB, int NBK){
  __shared__ int s[1024];
  int t = threadIdx.x;
  int v = (t < NB) ? bcnt[t] : 0;
  s[t] = v;
  __syncthreads();
  for (int off=1; off<1024; off<<=1){
    int add = (t >= off) ? s[t-off] : 0;
    __syncthreads();
    s[t] += add;
    __syncthreads();
  }
  if (t < NB) bbase[t] = s[t] - v;
  if (t == 1023){
    bbase[NB] = s[1023];
    rs2[NBK]  = s[1023];
  }
}
// column scan: bofs[i][j] -> exact placement base for (block i, bucket j)
__global__ void __launch_bounds__(256)
k_colscan(int* __restrict__ bofs, const int* __restrict__ bbase, int NB, int GC){
  __shared__ int part[256];
  int j = blockIdx.x, t = threadIdx.x;
  int K = (GC + 255) / 256;
  int beg = t*K, end = beg+K < GC ? beg+K : GC;
  int s = 0;
  for (int i=beg; i<end; i++) s += bofs[(size_t)i*NB + j];
  part[t] = s;
  __syncthreads();
  for (int off=1; off<256; off<<=1){
    int add = (t >= off) ? part[t-off] : 0;
    __syncthreads();
    part[t] += add;
    __syncthreads();
  }
  int run = bbase[j] + part[t] - s;
  for (int i=beg; i<end; i++){
    size_t idx = (size_t)i*NB + j;
    int v = bofs[idx];
    bofs[idx] = run;
    run += v;
  }
}
// Pass C: place packed (coloff<<22 | tile<<19 | row), single streaming pass.
__global__ void __launch_bounds__(256)
k_bkt_place(const int* __restrict__ ei, const int* __restrict__ flags,
            const int* __restrict__ bofs, int* __restrict__ pairs, int E, int NB){
  __shared__ int h[MAXNB];
  int t = threadIdx.x;
  size_t rowb = (size_t)blockIdx.x * NB;
  for (int j=t; j<NB; j+=256) h[j] = bofs[rowb + j];
  __syncthreads();
  int w64 = flags[0];
  long long base = (long long)blockIdx.x * CHUNK;
  for (int k0=0; k0<CHUNK; k0+=256*EB){
    int r[EB], c[EB]; bool v[EB];
    #pragma unroll
    for (int u=0;u<EB;u++){
      long long i = base + k0 + u*256 + t;
      v[u] = (i < E);
      r[u] = v[u] ? ld_row(ei, E, i, w64) : 0;
      c[u] = v[u] ? ld_col(ei, E, i, w64) : 0;
    }
    int pos[EB];
    #pragma unroll
    for (int u=0;u<EB;u++) pos[u] = v[u] ? atomicAdd(&h[c[u]>>BSHIFT], 1) : 0;
    #pragma unroll
    for (int u=0;u<EB;u++)
      if (v[u]) pairs[pos[u]] = r[u] | ((r[u]>>TSHIFT)<<19) | ((c[u] & (BSPAN-1)) << 22);
  }
}
// key = (tile, coloff) -> tile-major order within bucket
__device__ __forceinline__ int tkey(int pk){
  return (((pk>>19)&7)<<BSHIFT) | (pk>>22);
}
// Pass D: one block per bucket — sort by (tile, col); dump rs2 segment
// starts; emit src rows; dinv per col.
__global__ void __launch_bounds__(256)
k_group(const int* __restrict__ pairs, const int* __restrict__ bbase,
        float* __restrict__ dinv, int* __restrict__ src,
        int* __restrict__ rs2, int N){
  __shared__ int cnt[NKEY];   // 16 KB
  __shared__ int cur[NKEY];   // 16 KB
  __shared__ int part[256];
  int b = blockIdx.x, t = threadIdx.x;
  int lo = bbase[b], hi = bbase[b+1];
  #pragma unroll
  for (int u=0;u<NKEY/256;u++) cnt[u*256+t] = 0;
  __syncthreads();
  {
    int p = lo + t;
    for (; p + 3*256 < hi; p += 4*256){
      int k0=tkey(pairs[p]), k1=tkey(pairs[p+256]), k2=tkey(pairs[p+512]), k3=tkey(pairs[p+768]);
      atomicAdd(&cnt[k0],1); atomicAdd(&cnt[k1],1);
      atomicAdd(&cnt[k2],1); atomicAdd(&cnt[k3],1);
    }
    for (; p < hi; p += 256) atomicAdd(&cnt[tkey(pairs[p])],1);
  }
  __syncthreads();
  int loc[16]; int s = 0;
  #pragma unroll
  for (int u=0;u<16;u++){ loc[u] = cnt[t*16+u]; s += loc[u]; }
  part[t] = s;
  __syncthreads();
  for (int off=1; off<256; off<<=1){
    int add = (t >= off) ? part[t-off] : 0;
    __syncthreads();
    part[t] += add;
    __syncthreads();
  }
  int run = lo + part[t] - s;
  #pragma unroll
  for (int u=0;u<16;u++){ cur[t*16+u] = run; run += loc[u]; }
  __syncthreads();
  // dump segment starts + dinv (cur still pristine here)
  {
    size_t rb = (size_t)b * NKEY;
    #pragma unroll
    for (int u=0;u<16;u++){ int k = t*16+u; rs2[rb + k] = cur[k]; }
    int col0 = b << BSHIFT;
    #pragma unroll
    for (int u=0;u<2;u++){
      int j = 2*t + u;
      int colg = col0 + j;
      if (colg < N){
        int deg = 0;
        #pragma unroll
        for (int tt=0; tt<NTILE; tt++) deg += cnt[(tt<<BSHIFT) | j];
        dinv[colg] = rsqrtf((float)deg + 1.0f);
      }
    }
  }
  __syncthreads();
  {
    int p = lo + t;
    for (; p + 3*256 < hi; p += 4*256){
      int pk0=pairs[p], pk1=pairs[p+256], pk2=pairs[p+512], pk3=pairs[p+768];
      int q0 = atomicAdd(&cur[tkey(pk0)], 1);
      int q1 = atomicAdd(&cur[tkey(pk1)], 1);
      int q2 = atomicAdd(&cur[tkey(pk2)], 1);
      int q3 = atomicAdd(&cur[tkey(pk3)], 1);
      src[q0] = pk0 & 0x7FFFF; src[q1] = pk1 & 0x7FFFF;
      src[q2] = pk2 & 0x7FFFF; src[q3] = pk3 & 0x7FFFF;
    }
    for (; p < hi; p += 256){
      int pk = pairs[p];
      int q = atomicAdd(&cur[tkey(pk)], 1);
      src[q] = pk & 0x7FFFF;
    }
  }
}

// ---- lin-first: g = dinv * (x @ W0 + b0), row stride 16 ------------------
template<typename GT>
__global__ void k_lin_first(const void* __restrict__ x, const void* __restrict__ W,
                            const void* __restrict__ b, const int* __restrict__ flags,
                            const float* __restrict__ dinv,
                            GT* __restrict__ g, int n){
  __shared__ float Ws[4*EMB];
  __shared__ float bs[EMB];
  int t = threadIdx.x;
  int isbf = flags[1];
  if (t < 4*EMB) Ws[t] = ldf(W, t, isbf);
  if (t < EMB)   bs[t] = ldf(b, t, isbf);
  __syncthreads();
  int i = blockIdx.x*blockDim.x + t;
  if (i >= n) return;
  float xi[4];
  #pragma unroll
  for (int k=0;k<4;k++) xi[k] = ldf(x, (size_t)i*4+k, isbf);
  float d = dinv[i];
  float o[12];
  #pragma unroll
  for (int j=0;j<EMB;j++){
    float h = bs[j];
    #pragma unroll
    for (int k=0;k<4;k++) h = fmaf(xi[k], Ws[k*EMB+j], h);
    o[j] = d*h;
  }
  rowstore(g + (size_t)i*16, o);
}

// ---- lin-mid (fallback path) ---------------------------------------------
template<typename GT>
__global__ void k_lin_mid(const float* __restrict__ acc, const void* __restrict__ W,
                          const void* __restrict__ b, const int* __restrict__ flags,
                          const float* __restrict__ dinv,
                          GT* __restrict__ g, int n){
  __shared__ float Ws[EMB*EMB];
  __shared__ float bs[EMB];
  int t = threadIdx.x;
  int isbf = flags[1];
  if (t < EMB*EMB) Ws[t] = ldf(W, t, isbf);
  if (t < EMB)     bs[t] = ldf(b, t, isbf);
  __syncthreads();
  int i = blockIdx.x*blockDim.x + t;
  if (i >= n) return;
  float xi[EMB];
  size_t abase = (size_t)i*EMB;
  #pragma unroll
  for (int k=0;k<EMB;k++) xi[k] = tanhf(acc[abase+k]);
  float d = dinv[i];
  float o[12];
  #pragma unroll
  for (int j=0;j<EMB;j++){
    float h = bs[j];
    #pragma unroll
    for (int k=0;k<EMB;k++) h = fmaf(xi[k], Ws[k*EMB+j], h);
    o[j] = d*h;
  }
  rowstore(g + (size_t)i*16, o);
}

// ---- segment sum: add rows src[s..e) into a[12] --------------------------
template<typename GT>
__device__ __forceinline__ void seg_sum(const GT* __restrict__ gin,
                                        const int* __restrict__ src,
                                        int s, int e, float a[12]){
  int p = s;
  for (; p+1 < e; p += 2){
    int r0 = src[p], r1 = src[p+1];
    float h0[12], h1[12];
    rowload(gin + (size_t)r0*16, h0);
    rowload(gin + (size_t)r1*16, h1);
    #pragma unroll
    for (int j=0;j<12;j++) a[j] += h0[j] + h1[j];
  }
  if (p < e){
    int r = src[p];
    float h[12];
    rowload(gin + (size_t)r*16, h);
    #pragma unroll
    for (int j=0;j<12;j++) a[j] += h[j];
  }
}

// ---- epilogue: self-loop + tanh (+MLP) + store ---------------------------
template<typename GT, int MODE>
__device__ __forceinline__ void finish_col(int c, int n, const float a[12],
                                           const GT* __restrict__ gin,
                                           const float* __restrict__ dinv,
                                           const float* Ws, const float* bs,
                                           void* __restrict__ outp){
  if (c >= n) return;
  float v[12];
  rowload(gin + (size_t)c*16, v);         // self-loop
  #pragma unroll
  for (int j=0;j<12;j++) v[j] += a[j];
  float d = dinv[c];
  if (MODE == 0){
    float h[12];
    #pragma unroll
    for (int k=0;k<12;k++) h[k] = tanhf(d*v[k]);
    float o[12];
    #pragma unroll
    for (int j=0;j<12;j++){
      float w = bs[j];
      #pragma unroll
      for (int k=0;k<12;k++) w = fmaf(h[k], Ws[k*EMB+j], w);
      o[j] = d*w;
    }
    rowstore((GT*)outp + (size_t)c*16, o);
  } else {
    float4* ap = (float4*)((float*)outp + (size_t)c*EMB);
    ap[0] = make_float4(tanhf(d*v[0]), tanhf(d*v[1]), tanhf(d*v[2]),  tanhf(d*v[3]));
    ap[1] = make_float4(tanhf(d*v[4]), tanhf(d*v[5]), tanhf(d*v[6]),  tanhf(d*v[7]));
    ap[2] = make_float4(tanhf(d*v[8]), tanhf(d*v[9]), tanhf(d*v[10]), tanhf(d*v[11]));
  }
}

// ---- tile-phased persistent gather ---------------------------------------
// Grid = GGRID blocks, 4/CU co-resident. Outer loop over source tiles with a
// grid phase barrier -> chip-wide working set = one 2MB tile (L2-resident).
// Each thread owns up to 2 columns; accumulators live in registers.
// MODE 0: conv -> tanh -> @W+b -> *dinv -> gout (stride 16, GT)
// MODE 1: conv -> tanh -> acc (f32, stride 12)
template<typename GT, int MODE>
__global__ void __launch_bounds__(256, 4)
k_gather_phase(const int* __restrict__ rs2, const int* __restrict__ src,
               const float* __restrict__ dinv, const GT* __restrict__ gin,
               const void* __restrict__ W, const void* __restrict__ b,
               const int* __restrict__ flags, void* __restrict__ outp,
               int n, int nt, int* __restrict__ bar){
  __shared__ float Ws[EMB*EMB];
  __shared__ float bs[EMB];
  int t = threadIdx.x;
  if (MODE == 0){
    int isbf = flags[1];
    if (t < EMB*EMB) Ws[t] = ldf(W, t, isbf);
    if (t < EMB)     bs[t] = ldf(b, t, isbf);
  }
  __syncthreads();
  int c0 = blockIdx.x*256 + t;
  int c1 = c0 + GSTRIDE;
  float a0[12], a1[12];
  #pragma unroll
  for (int j=0;j<12;j++){ a0[j]=0.f; a1[j]=0.f; }
  for (int tau=0; tau<nt; tau++){
    if (c0 < n){
      int idx = ((c0>>BSHIFT)<<12) + (tau<<BSHIFT) + (c0 & (BSPAN-1));
      seg_sum<GT>(gin, src, rs2[idx], rs2[idx+1], a0);
    }
    if (c1 < n){
      int idx = ((c1>>BSHIFT)<<12) + (tau<<BSHIFT) + (c1 & (BSPAN-1));
      seg_sum<GT>(gin, src, rs2[idx], rs2[idx+1], a1);
    }
    if (tau+1 < nt) gridbar(bar + 2*tau, (int)gridDim.x);
  }
  finish_col<GT,MODE>(c0, n, a0, gin, dinv, Ws, bs, outp);
  finish_col<GT,MODE>(c1, n, a1, gin, dinv, Ws, bs, outp);
}

// ---- FALLBACK (small ws): atomic scatter path ----------------------------
__global__ void k_cnt_deg(const int* __restrict__ ei, const int* __restrict__ flags,
                          int* __restrict__ cnt, int e){
  int i = blockIdx.x*blockDim.x + threadIdx.x;
  if (i >= e) return;
  atomicAdd(&cnt[ld_col(ei, e, i, flags[0])], 1);
}
__global__ void k_dinv_from_cnt(const int* __restrict__ cnt, float* __restrict__ dinv, int n){
  int i = blockIdx.x*blockDim.x + threadIdx.x;
  if (i < n) dinv[i] = rsqrtf((float)(cnt[i] + 1));
}
__global__ void k_selfinit(const float* __restrict__ g, const float* __restrict__ dinv,
                           float* __restrict__ acc, int n){
  int i = blockIdx.x*blockDim.x + threadIdx.x;
  if (i >= n) return;
  float d = dinv[i];
  float h[12]; rowload(g + (size_t)i*16, h);
  #pragma unroll
  for (int j=0;j<EMB;j++) acc[(size_t)i*EMB+j] = d*h[j];
}
__global__ void k_scatter(const int* __restrict__ ei, const int* __restrict__ flags,
                          const float* __restrict__ dinv, const float* __restrict__ g,
                          float* __restrict__ acc, int e){
  int i = blockIdx.x*blockDim.x + threadIdx.x;
  if (i >= e) return;
  int w64 = flags[0];
  int r = ld_row(ei, e, i, w64);
  int c = ld_col(ei, e, i, w64);
  float w = dinv[c];
  float h[12];
  rowload(g + (size_t)r*16, h);
  float* ap = acc + (size_t)c*EMB;
  #pragma unroll
  for (int j=0;j<EMB;j++) atomicAdd(ap+j, w*h[j]);
}

// ---- pooling + output head ----------------------------------------------
template<int DOTANH>
__global__ void __launch_bounds__(256)
k_pool(const float* __restrict__ acc, const int* __restrict__ batch,
       const int* __restrict__ flags,
       const void* __restrict__ Wout, const void* __restrict__ bout,
       void* __restrict__ out, int n){
  int g = blockIdx.x;
  int w64  = flags[0];
  int isbf = flags[1];
  __shared__ int se[2];
  __shared__ float smax[4][EMB];
  __shared__ float ssum[4][EMB];
  __shared__ float hid[2*EMB];
  if (threadIdx.x == 0){
    int lo=0, hi=n;
    while (lo<hi){ int m=(lo+hi)>>1; if (ld_batch(batch,m,w64) < g) lo=m+1; else hi=m; }
    se[0]=lo;
    int lo2=lo; hi=n;
    while (lo2<hi){ int m=(lo2+hi)>>1; if (ld_batch(batch,m,w64) < g+1) lo2=m+1; else hi=m; }
    se[1]=lo2;
  }
  __syncthreads();
  int start=se[0], end=se[1];
  float lmax[EMB], lsum[EMB];
  #pragma unroll
  for (int j=0;j<EMB;j++){ lmax[j]=-3.0e38f; lsum[j]=0.f; }
  for (int i=start+(int)threadIdx.x; i<end; i+=blockDim.x){
    size_t base=(size_t)i*EMB;
    #pragma unroll
    for (int j=0;j<EMB;j++){
      float h = DOTANH ? tanhf(acc[base+j]) : acc[base+j];
      lmax[j] = fmaxf(lmax[j], h);
      lsum[j] += h;
    }
  }
  #pragma unroll
  for (int m=32;m>=1;m>>=1){
    #pragma unroll
    for (int j=0;j<EMB;j++){
      lmax[j] = fmaxf(lmax[j], __shfl_xor(lmax[j], m, 64));
      lsum[j] += __shfl_xor(lsum[j], m, 64);
    }
  }
  int wave = threadIdx.x>>6, lane = threadIdx.x&63;
  if (lane==0){
    #pragma unroll
    for (int j=0;j<EMB;j++){ smax[wave][j]=lmax[j]; ssum[wave][j]=lsum[j]; }
  }
  __syncthreads();
  int cnt = end-start;
  if (threadIdx.x < EMB){
    int j = threadIdx.x;
    float mx=smax[0][j], sm=ssum[0][j];
    #pragma unroll
    for (int w=1;w<4;w++){ mx=fmaxf(mx,smax[w][j]); sm+=ssum[w][j]; }
    if (cnt <= 0){ mx = 0.f; sm = 0.f; }
    float mean = sm / fmaxf((float)cnt, 1.0f);
    hid[j]     = mx;
    hid[EMB+j] = mean;
    stout(out, (size_t)NG*NCLS + (size_t)g*2*EMB + j,       mx,   isbf);
    stout(out, (size_t)NG*NCLS + (size_t)g*2*EMB + EMB + j, mean, isbf);
  }
  __syncthreads();
  if (threadIdx.x < NCLS){
    int c = threadIdx.x;
    float o = ldf(bout, c, isbf);
    #pragma unroll
    for (int k=0;k<2*EMB;k++) o = fmaf(hid[k], ldf(Wout, (size_t)k*NCLS+c, isbf), o);
    stout(out, (size_t)g*NCLS + c, o, isbf);
  }
}

__global__ void k_zero_out_noflags(void* __restrict__ out, int m){
  int i = blockIdx.x*blockDim.x + threadIdx.x;
  if (i < m) ((float*)out)[i] = 0.0f;
}

// ---- CSR build (shared) --------------------------------------------------
static void build_csr(const int* ei, const void* x, int* flags, int* bcnt, int* bbase,
                      int* bofs, float* dinv, int* src, int* pairs, int* rs2,
                      int* bar, int N, int E, int NB, hipStream_t stream){
  const int TB = 256;
  const int gc = (E + CHUNK - 1) / CHUNK;
  const int NBK = NB * NKEY;
  k_detect      <<<1, 64, 0, stream>>>(ei, (const unsigned short*)x, flags);
  k_zero_i      <<<(NB+TB-1)/TB, TB, 0, stream>>>(bcnt, NB);
  k_zero_i      <<<1, 64, 0, stream>>>(bar, 64);
  k_bkt_count   <<<gc, TB, 0, stream>>>(ei, flags, bcnt, bofs, E, NB);
  k_bkt_scan_par<<<1, 1024, 0, stream>>>(bcnt, bbase, rs2, NB, NBK);
  k_colscan     <<<NB, TB, 0, stream>>>(bofs, bbase, NB, gc);
  k_bkt_place   <<<gc, TB, 0, stream>>>(ei, flags, bofs, pairs, E, NB);
  k_group       <<<NB, TB, 0, stream>>>(pairs, bbase, dinv, src, rs2, N);
}

static size_t alignup(size_t v){ return (v + 63) & ~(size_t)63; }
static size_t maxsz(size_t a, size_t b){ return a > b ? a : b; }

extern "C" void kernel_launch(void* const* d_in, const int* in_sizes, int n_in,
                              void* d_out, int out_size, void* d_ws, size_t ws_size,
                              hipStream_t stream) {
  const void* x     = d_in[0];
  const int*  ei    = (const int*)d_in[1];
  const int*  batch = (const int*)d_in[2];
  const void* W0 = d_in[3];  const void* b0 = d_in[4];
  const void* W1 = d_in[5];  const void* b1 = d_in[6];
  const void* W2 = d_in[7];  const void* b2 = d_in[8];
  const void* W3 = d_in[9];  const void* b3 = d_in[10];
  const void* Wout = d_in[11]; const void* bout = d_in[12];

  const int N = in_sizes[0] / 4;
  const int E = in_sizes[1] / 2;
  const int NB = (N + BSPAN - 1) >> BSHIFT;
  const int GC = (E + CHUNK - 1) / CHUNK;
  const int TB = 256;
  const int gn = (N + TB - 1) / TB;
  const int nt = (N + (1<<TSHIFT) - 1) >> TSHIFT;

  char* base = (char*)d_ws;

  size_t o_flags  = 0;
  size_t o_bar    = alignup(o_flags + 64);
  size_t o_dinv   = alignup(o_bar + 64*4);
  size_t o_bcnt   = alignup(o_dinv + (size_t)N*4);
  size_t o_bbase  = alignup(o_bcnt + (size_t)NB*4);
  size_t o_bofs   = alignup(o_bbase + ((size_t)NB+1)*4);
  size_t o_rs2    = alignup(o_bofs + (size_t)GC*NB*4);
  size_t o_src    = alignup(o_rs2 + ((size_t)NB*NKEY + 1)*4);
  size_t o_buf    = alignup(o_src + (size_t)E*4);     // pairs aliases from here

  int* flags  = (int*)(base+o_flags);
  int* bar    = (int*)(base+o_bar);
  float* dinv = (float*)(base+o_dinv);
  int* bcnt   = (int*)(base+o_bcnt);
  int* bbase  = (int*)(base+o_bbase);
  int* bofs   = (int*)(base+o_bofs);
  int* rs2    = (int*)(base+o_rs2);
  int* src    = (int*)(base+o_src);
  int* pairs  = (int*)(base+o_buf);

  bool fast_ok = (N < (1<<19)) && (NB <= MAXNB) && (nt <= NTILE);

  // T1: tile-phased, bf16 g double-buffered. acc aliases R0.
  {
    size_t szR0 = maxsz((size_t)N*16*2, (size_t)N*EMB*4);
    size_t o_gB = alignup(o_buf + szR0);
    size_t need = o_gB + (size_t)N*16*2;
    bool pairs_fit = (size_t)E*4 <= need - o_buf;
    if (fast_ok && pairs_fit && ws_size >= need){
      bf16*  gA  = (bf16*)(base+o_buf);
      bf16*  gB  = (bf16*)(base+o_gB);
      float* acc = (float*)(base+o_buf);
      build_csr(ei, x, flags, bcnt, bbase, bofs, dinv, src, pairs, rs2, bar, N, E, NB, stream);
      k_lin_first<bf16><<<gn, TB, 0, stream>>>(x, W0, b0, flags, dinv, gA, N);
      k_gather_phase<bf16,0><<<GGRID, TB, 0, stream>>>(rs2, src, dinv, gA, W1, b1, flags, gB, N, nt, bar);
      k_gather_phase<bf16,0><<<GGRID, TB, 0, stream>>>(rs2, src, dinv, gB, W2, b2, flags, gA, N, nt, bar+16);
      k_gather_phase<bf16,0><<<GGRID, TB, 0, stream>>>(rs2, src, dinv, gA, W3, b3, flags, gB, N, nt, bar+32);
      k_gather_phase<bf16,1><<<GGRID, TB, 0, stream>>>(rs2, src, dinv, gB, 0, 0, flags, acc, N, nt, bar+48);
      k_pool<0><<<NG, 256, 0, stream>>>(acc, batch, flags, Wout, bout, d_out, N);
      return;
    }
  }

  // T2: tile-phased, f32 g double-buffered. acc aliases gA.
  {
    size_t o_gA = o_buf;
    size_t o_gB = alignup(o_gA + (size_t)N*16*4);
    size_t need = o_gB + (size_t)N*16*4;
    bool pairs_fit = (size_t)E*4 <= need - o_buf;
    if (fast_ok && pairs_fit && ws_size >= need){
      float* gA  = (float*)(base+o_gA);
      float* gB  = (float*)(base+o_gB);
      float* acc = gA;
      build_csr(ei, x, flags, bcnt, bbase, bofs, dinv, src, pairs, rs2, bar, N, E, NB, stream);
      k_lin_first<float><<<gn, TB, 0, stream>>>(x, W0, b0, flags, dinv, gA, N);
      k_gather_phase<float,0><<<GGRID, TB, 0, stream>>>(rs2, src, dinv, gA, W1, b1, flags, gB, N, nt, bar);
      k_gather_phase<float,0><<<GGRID, TB, 0, stream>>>(rs2, src, dinv, gB, W2, b2, flags, gA, N, nt, bar+16);
      k_gather_phase<float,0><<<GGRID, TB, 0, stream>>>(rs2, src, dinv, gA, W3, b3, flags, gB, N, nt, bar+32);
      k_gather_phase<float,1><<<GGRID, TB, 0, stream>>>(rs2, src, dinv, gB, 0, 0, flags, acc, N, nt, bar+48);
      k_pool<0><<<NG, 256, 0, stream>>>(acc, batch, flags, Wout, bout, d_out, N);
      return;
    }
  }

  // T4: atomic-scatter fallback
  {
    size_t f_cnt  = alignup(o_dinv + (size_t)N*4);
    size_t f_g    = alignup(f_cnt + (size_t)N*4);
    size_t f_acc  = alignup(f_g + (size_t)N*16*4);
    size_t f_end  = f_acc + (size_t)N*EMB*4;
    const int ge = (E + TB - 1) / TB;
    int* cnt = (int*)(base+f_cnt);

    if (ws_size >= f_end){
      float* g   = (float*)(base+f_g);
      float* acc = (float*)(base+f_acc);
      k_detect  <<<1, 64, 0, stream>>>(ei, (const unsigned short*)x, flags);
      k_zero_i  <<<gn, TB, 0, stream>>>(cnt, N);
      k_cnt_deg <<<ge, TB, 0, stream>>>(ei, flags, cnt, E);
      k_dinv_from_cnt<<<gn, TB, 0, stream>>>(cnt, dinv, N);
      k_lin_first<float><<<gn, TB, 0, stream>>>(x, W0, b0, flags, dinv, g, N);
      k_selfinit <<<gn, TB, 0, stream>>>(g, dinv, acc, N);
      k_scatter  <<<ge, TB, 0, stream>>>(ei, flags, dinv, g, acc, E);
      const void* Wl[3] = {W1,W2,W3};
      const void* bl[3] = {b1,b2,b3};
      for (int l=0;l<3;l++){
        k_lin_mid<float><<<gn, TB, 0, stream>>>(acc, Wl[l], bl[l], flags, dinv, g, N);
        k_selfinit<<<gn, TB, 0, stream>>>(g, dinv, acc, N);
        k_scatter <<<ge, TB, 0, stream>>>(ei, flags, dinv, g, acc, E);
      }
      k_pool<1><<<NG, 256, 0, stream>>>(acc, batch, flags, Wout, bout, d_out, N);
    } else {
      k_zero_out_noflags<<<(out_size+255)/256, 256, 0, stream>>>(d_out, out_size);
    }
  }
}

// Round 4
// 600.912 us; speedup vs baseline: 7.5671x; 7.5671x over previous
//
#include <hip/hip_runtime.h>
#include <hip/hip_bf16.h>
#include <math.h>

typedef __hip_bfloat16 bf16;

#define EMB 12
#define NCLS 17
#define NG 1000
#define BSHIFT 9
#define BSPAN 512            // cols per bucket
#define MAXNB 1024           // max buckets (N <= 524287)
#define CHUNK 16384          // edges per block in count/place
#define EB 8                 // edge batch (MLP) in count/place
#define TSHIFT 16            // source tile = 65536 nodes = 2 MB bf16 (fits 4MB XCD L2)
#define NTILE 8              // max tiles (N < 2^19)
#define NKEY (BSPAN*NTILE)   // 4096 sort keys in k_group

__device__ __forceinline__ float b2f(bf16 v){ return __bfloat162float(v); }

__device__ __forceinline__ unsigned short f2bf_rne(float f){
  unsigned int u = __float_as_uint(f);
  unsigned int r = (u + 0x7FFFu + ((u >> 16) & 1u)) >> 16;
  return (unsigned short)r;
}

__device__ __forceinline__ float ldf(const void* p, size_t i, int isbf){
  if (isbf) return b2f(((const bf16*)p)[i]);
  return ((const float*)p)[i];
}
__device__ __forceinline__ void stout(void* p, size_t i, float v, int isbf){
  if (isbf) ((unsigned short*)p)[i] = f2bf_rne(v);
  else      ((float*)p)[i] = v;
}

// ---- row load/store, stride 16 elements ----------------------------------
__device__ __forceinline__ void rowload(const float* p, float o[12]){
  const float4* q = (const float4*)p;
  float4 a = q[0], b = q[1], c = q[2];
  o[0]=a.x;o[1]=a.y;o[2]=a.z;o[3]=a.w;o[4]=b.x;o[5]=b.y;o[6]=b.z;o[7]=b.w;
  o[8]=c.x;o[9]=c.y;o[10]=c.z;o[11]=c.w;
}
__device__ __forceinline__ void rowload(const bf16* p, float o[12]){
  const uint4* q = (const uint4*)p;       // 32B row, 16B aligned
  uint4 u0 = q[0];
  uint2 u1 = *(const uint2*)(q+1);
  o[0] =__uint_as_float(u0.x<<16); o[1] =__uint_as_float(u0.x&0xFFFF0000u);
  o[2] =__uint_as_float(u0.y<<16); o[3] =__uint_as_float(u0.y&0xFFFF0000u);
  o[4] =__uint_as_float(u0.z<<16); o[5] =__uint_as_float(u0.z&0xFFFF0000u);
  o[6] =__uint_as_float(u0.w<<16); o[7] =__uint_as_float(u0.w&0xFFFF0000u);
  o[8] =__uint_as_float(u1.x<<16); o[9] =__uint_as_float(u1.x&0xFFFF0000u);
  o[10]=__uint_as_float(u1.y<<16); o[11]=__uint_as_float(u1.y&0xFFFF0000u);
}
__device__ __forceinline__ void rowstore(float* p, const float o[12]){
  float4* q = (float4*)p;
  q[0] = make_float4(o[0],o[1],o[2],o[3]);
  q[1] = make_float4(o[4],o[5],o[6],o[7]);
  q[2] = make_float4(o[8],o[9],o[10],o[11]);
}
__device__ __forceinline__ void rowstore(bf16* p, const float o[12]){
  unsigned int u[6];
  #pragma unroll
  for (int k=0;k<6;k++)
    u[k] = (unsigned int)f2bf_rne(o[2*k]) | ((unsigned int)f2bf_rne(o[2*k+1])<<16);
  uint2* q = (uint2*)p;
  q[0] = make_uint2(u[0],u[1]);
  q[1] = make_uint2(u[2],u[3]);
  q[2] = make_uint2(u[4],u[5]);
}

// ---- runtime dtype detection ---------------------------------------------
__global__ void k_detect(const int* __restrict__ ei, const unsigned short* __restrict__ xh,
                         int* __restrict__ flags){
  if (blockIdx.x==0 && threadIdx.x==0){
    int z = 1;
    for (int k=1; k<32; k+=2) z &= (ei[k]==0);
    flags[0] = z;
    int hits = 0;
    for (int k=0; k<32; k+=2){
      int e = (xh[k] >> 7) & 0xFF;
      if (e >= 100 && e <= 140) hits++;
    }
    flags[1] = (hits >= 12) ? 1 : 0;
  }
}
__device__ __forceinline__ int ld_row(const int* ei, long long E, long long i, int w64){
  return w64 ? ei[2*i] : ei[i];
}
__device__ __forceinline__ int ld_col(const int* ei, long long E, long long i, int w64){
  return w64 ? ei[2*E + 2*i] : ei[E + i];
}
__device__ __forceinline__ int ld_batch(const int* b, long long i, int w64){
  return w64 ? b[2*i] : b[i];
}

// ---- bucketed CSR build (no per-edge global atomics) ---------------------
__global__ void k_zero_i(int* __restrict__ p, int n){
  int i = blockIdx.x*blockDim.x + threadIdx.x;
  if (i < n) p[i] = 0;
}
// Pass A: per-block LDS histogram; writes per-block counts (bofs) + totals.
__global__ void __launch_bounds__(256)
k_bkt_count(const int* __restrict__ ei, const int* __restrict__ flags,
            int* __restrict__ bcnt, int* __restrict__ bofs, int E, int NB){
  __shared__ int h[MAXNB];
  int t = threadIdx.x;
  for (int j=t; j<NB; j+=256) h[j] = 0;
  __syncthreads();
  int w64 = flags[0];
  long long base = (long long)blockIdx.x * CHUNK;
  for (int k0=0; k0<CHUNK; k0+=256*EB){
    int c[EB]; bool v[EB];
    #pragma unroll
    for (int u=0;u<EB;u++){
      long long i = base + k0 + u*256 + t;
      v[u] = (i < E);
      c[u] = v[u] ? ld_col(ei, E, i, w64) : 0;
    }
    #pragma unroll
    for (int u=0;u<EB;u++) if (v[u]) atomicAdd(&h[c[u]>>BSHIFT], 1);
  }
  __syncthreads();
  size_t rowb = (size_t)blockIdx.x * NB;
  for (int j=t; j<NB; j+=256){
    int c = h[j];
    bofs[rowb + j] = c;
    if (c > 0) atomicAdd(&bcnt[j], c);
  }
}
// bucket-total scan (single block); also writes rs2 sentinel.
__global__ void __launch_bounds__(1024)
k_bkt_scan_par(const int* __restrict__ bcnt, int* __restrict__ bbase,
               int* __restrict__ rs2, int NB, int NBK){
  __shared__ int s[1024];
  int t = threadIdx.x;
  int v = (t < NB) ? bcnt[t] : 0;
  s[t] = v;
  __syncthreads();
  for (int off=1; off<1024; off<<=1){
    int add = (t >= off) ? s[t-off] : 0;
    __syncthreads();
    s[t] += add;
    __syncthreads();
  }
  if (t < NB) bbase[t] = s[t] - v;
  if (t == 1023){
    bbase[NB] = s[1023];
    rs2[NBK]  = s[1023];
  }
}
// column scan: bofs[i][j] -> exact placement base for (block i, bucket j)
__global__ void __launch_bounds__(256)
k_colscan(int* __restrict__ bofs, const int* __restrict__ bbase, int NB, int GC){
  __shared__ int part[256];
  int j = blockIdx.x, t = threadIdx.x;
  int K = (GC + 255) / 256;
  int beg = t*K, end = beg+K < GC ? beg+K : GC;
  int s = 0;
  for (int i=beg; i<end; i++) s += bofs[(size_t)i*NB + j];
  part[t] = s;
  __syncthreads();
  for (int off=1; off<256; off<<=1){
    int add = (t >= off) ? part[t-off] : 0;
    __syncthreads();
    part[t] += add;
    __syncthreads();
  }
  int run = bbase[j] + part[t] - s;
  for (int i=beg; i<end; i++){
    size_t idx = (size_t)i*NB + j;
    int v = bofs[idx];
    bofs[idx] = run;
    run += v;
  }
}
// Pass C: place packed (coloff<<22 | tile<<19 | row), single streaming pass.
__global__ void __launch_bounds__(256)
k_bkt_place(const int* __restrict__ ei, const int* __restrict__ flags,
            const int* __restrict__ bofs, int* __restrict__ pairs, int E, int NB){
  __shared__ int h[MAXNB];
  int t = threadIdx.x;
  size_t rowb = (size_t)blockIdx.x * NB;
  for (int j=t; j<NB; j+=256) h[j] = bofs[rowb + j];
  __syncthreads();
  int w64 = flags[0];
  long long base = (long long)blockIdx.x * CHUNK;
  for (int k0=0; k0<CHUNK; k0+=256*EB){
    int r[EB], c[EB]; bool v[EB];
    #pragma unroll
    for (int u=0;u<EB;u++){
      long long i = base + k0 + u*256 + t;
      v[u] = (i < E);
      r[u] = v[u] ? ld_row(ei, E, i, w64) : 0;
      c[u] = v[u] ? ld_col(ei, E, i, w64) : 0;
    }
    int pos[EB];
    #pragma unroll
    for (int u=0;u<EB;u++) pos[u] = v[u] ? atomicAdd(&h[c[u]>>BSHIFT], 1) : 0;
    #pragma unroll
    for (int u=0;u<EB;u++)
      if (v[u]) pairs[pos[u]] = r[u] | ((r[u]>>TSHIFT)<<19) | ((c[u] & (BSPAN-1)) << 22);
  }
}
// key = (tile, coloff) -> tile-major order within bucket
__device__ __forceinline__ int tkey(int pk){
  return (((pk>>19)&7)<<BSHIFT) | (pk>>22);
}
// Pass D: one block per bucket — sort by (tile, col); dump rs2 segment
// starts; emit src rows; dinv per col.
__global__ void __launch_bounds__(256)
k_group(const int* __restrict__ pairs, const int* __restrict__ bbase,
        float* __restrict__ dinv, int* __restrict__ src,
        int* __restrict__ rs2, int N){
  __shared__ int cnt[NKEY];   // 16 KB
  __shared__ int cur[NKEY];   // 16 KB
  __shared__ int part[256];
  int b = blockIdx.x, t = threadIdx.x;
  int lo = bbase[b], hi = bbase[b+1];
  #pragma unroll
  for (int u=0;u<NKEY/256;u++) cnt[u*256+t] = 0;
  __syncthreads();
  {
    int p = lo + t;
    for (; p + 3*256 < hi; p += 4*256){
      int k0=tkey(pairs[p]), k1=tkey(pairs[p+256]), k2=tkey(pairs[p+512]), k3=tkey(pairs[p+768]);
      atomicAdd(&cnt[k0],1); atomicAdd(&cnt[k1],1);
      atomicAdd(&cnt[k2],1); atomicAdd(&cnt[k3],1);
    }
    for (; p < hi; p += 256) atomicAdd(&cnt[tkey(pairs[p])],1);
  }
  __syncthreads();
  int loc[16]; int s = 0;
  #pragma unroll
  for (int u=0;u<16;u++){ loc[u] = cnt[t*16+u]; s += loc[u]; }
  part[t] = s;
  __syncthreads();
  for (int off=1; off<256; off<<=1){
    int add = (t >= off) ? part[t-off] : 0;
    __syncthreads();
    part[t] += add;
    __syncthreads();
  }
  int run = lo + part[t] - s;
  #pragma unroll
  for (int u=0;u<16;u++){ cur[t*16+u] = run; run += loc[u]; }
  __syncthreads();
  // dump segment starts + dinv (cur still pristine here)
  {
    size_t rb = (size_t)b * NKEY;
    #pragma unroll
    for (int u=0;u<16;u++){ int k = t*16+u; rs2[rb + k] = cur[k]; }
    int col0 = b << BSHIFT;
    #pragma unroll
    for (int u=0;u<2;u++){
      int j = 2*t + u;
      int colg = col0 + j;
      if (colg < N){
        int deg = 0;
        #pragma unroll
        for (int tt=0; tt<NTILE; tt++) deg += cnt[(tt<<BSHIFT) | j];
        dinv[colg] = rsqrtf((float)deg + 1.0f);
      }
    }
  }
  __syncthreads();
  {
    int p = lo + t;
    for (; p + 3*256 < hi; p += 4*256){
      int pk0=pairs[p], pk1=pairs[p+256], pk2=pairs[p+512], pk3=pairs[p+768];
      int q0 = atomicAdd(&cur[tkey(pk0)], 1);
      int q1 = atomicAdd(&cur[tkey(pk1)], 1);
      int q2 = atomicAdd(&cur[tkey(pk2)], 1);
      int q3 = atomicAdd(&cur[tkey(pk3)], 1);
      src[q0] = pk0 & 0x7FFFF; src[q1] = pk1 & 0x7FFFF;
      src[q2] = pk2 & 0x7FFFF; src[q3] = pk3 & 0x7FFFF;
    }
    for (; p < hi; p += 256){
      int pk = pairs[p];
      int q = atomicAdd(&cur[tkey(pk)], 1);
      src[q] = pk & 0x7FFFF;
    }
  }
}

// ---- lin-first: g = dinv * (x @ W0 + b0), row stride 16 ------------------
template<typename GT>
__global__ void k_lin_first(const void* __restrict__ x, const void* __restrict__ W,
                            const void* __restrict__ b, const int* __restrict__ flags,
                            const float* __restrict__ dinv,
                            GT* __restrict__ g, int n){
  __shared__ float Ws[4*EMB];
  __shared__ float bs[EMB];
  int t = threadIdx.x;
  int isbf = flags[1];
  if (t < 4*EMB) Ws[t] = ldf(W, t, isbf);
  if (t < EMB)   bs[t] = ldf(b, t, isbf);
  __syncthreads();
  int i = blockIdx.x*blockDim.x + t;
  if (i >= n) return;
  float xi[4];
  #pragma unroll
  for (int k=0;k<4;k++) xi[k] = ldf(x, (size_t)i*4+k, isbf);
  float d = dinv[i];
  float o[12];
  #pragma unroll
  for (int j=0;j<EMB;j++){
    float h = bs[j];
    #pragma unroll
    for (int k=0;k<4;k++) h = fmaf(xi[k], Ws[k*EMB+j], h);
    o[j] = d*h;
  }
  rowstore(g + (size_t)i*16, o);
}

// ---- lin-mid (fallback path) ---------------------------------------------
template<typename GT>
__global__ void k_lin_mid(const float* __restrict__ acc, const void* __restrict__ W,
                          const void* __restrict__ b, const int* __restrict__ flags,
                          const float* __restrict__ dinv,
                          GT* __restrict__ g, int n){
  __shared__ float Ws[EMB*EMB];
  __shared__ float bs[EMB];
  int t = threadIdx.x;
  int isbf = flags[1];
  if (t < EMB*EMB) Ws[t] = ldf(W, t, isbf);
  if (t < EMB)     bs[t] = ldf(b, t, isbf);
  __syncthreads();
  int i = blockIdx.x*blockDim.x + t;
  if (i >= n) return;
  float xi[EMB];
  size_t abase = (size_t)i*EMB;
  #pragma unroll
  for (int k=0;k<EMB;k++) xi[k] = tanhf(acc[abase+k]);
  float d = dinv[i];
  float o[12];
  #pragma unroll
  for (int j=0;j<EMB;j++){
    float h = bs[j];
    #pragma unroll
    for (int k=0;k<EMB;k++) h = fmaf(xi[k], Ws[k*EMB+j], h);
    o[j] = d*h;
  }
  rowstore(g + (size_t)i*16, o);
}

// ---- segment tail: add rows src[p..e) into a[12], 2x unroll --------------
template<typename GT>
__device__ __forceinline__ void seg_tail(const GT* __restrict__ gin,
                                         const int* __restrict__ src,
                                         int p, int e, float a[12]){
  for (; p+1 < e; p += 2){
    int r0 = src[p], r1 = src[p+1];
    float h0[12], h1[12];
    rowload(gin + (size_t)r0*16, h0);
    rowload(gin + (size_t)r1*16, h1);
    #pragma unroll
    for (int j=0;j<12;j++) a[j] += h0[j] + h1[j];
  }
  if (p < e){
    int r = src[p];
    float h[12];
    rowload(gin + (size_t)r*16, h);
    #pragma unroll
    for (int j=0;j<12;j++) a[j] += h[j];
  }
}

// ---- dual segment sum: interleave two columns' segments (4 rows in flight)
template<typename GT>
__device__ __forceinline__ void seg_sum2(const GT* __restrict__ gin,
                                         const int* __restrict__ src,
                                         int p0, int e0, int p1, int e1,
                                         float a0[12], float a1[12]){
  while (p0+1 < e0 && p1+1 < e1){
    int r00 = src[p0], r01 = src[p0+1], r10 = src[p1], r11 = src[p1+1];
    float h00[12], h01[12], h10[12], h11[12];
    rowload(gin + (size_t)r00*16, h00);
    rowload(gin + (size_t)r01*16, h01);
    rowload(gin + (size_t)r10*16, h10);
    rowload(gin + (size_t)r11*16, h11);
    #pragma unroll
    for (int j=0;j<12;j++){ a0[j] += h00[j]+h01[j]; a1[j] += h10[j]+h11[j]; }
    p0 += 2; p1 += 2;
  }
  seg_tail<GT>(gin, src, p0, e0, a0);
  seg_tail<GT>(gin, src, p1, e1, a1);
}

// ---- epilogue: self-loop + tanh (+MLP) + store ---------------------------
template<typename GT, int MODE>
__device__ __forceinline__ void finish_col(int c, int n, const float a[12],
                                           const GT* __restrict__ gin,
                                           const float* __restrict__ dinv,
                                           const float* Ws, const float* bs,
                                           void* __restrict__ outp){
  if (c >= n) return;
  float v[12];
  rowload(gin + (size_t)c*16, v);         // self-loop
  #pragma unroll
  for (int j=0;j<12;j++) v[j] += a[j];
  float d = dinv[c];
  if (MODE == 0){
    float h[12];
    #pragma unroll
    for (int k=0;k<12;k++) h[k] = tanhf(d*v[k]);
    float o[12];
    #pragma unroll
    for (int j=0;j<12;j++){
      float w = bs[j];
      #pragma unroll
      for (int k=0;k<12;k++) w = fmaf(h[k], Ws[k*EMB+j], w);
      o[j] = d*w;
    }
    rowstore((GT*)outp + (size_t)c*16, o);
  } else {
    float4* ap = (float4*)((float*)outp + (size_t)c*EMB);
    ap[0] = make_float4(tanhf(d*v[0]), tanhf(d*v[1]), tanhf(d*v[2]),  tanhf(d*v[3]));
    ap[1] = make_float4(tanhf(d*v[4]), tanhf(d*v[5]), tanhf(d*v[6]),  tanhf(d*v[7]));
    ap[2] = make_float4(tanhf(d*v[8]), tanhf(d*v[9]), tanhf(d*v[10]), tanhf(d*v[11]));
  }
}

// ---- XCD-rotated tile gather (no barriers) -------------------------------
// Block handles 512 adjacent cols (2/thread). Tile visit order rotates by
// blockIdx&7 (~XCD id): blocks sharing an XCD L2 walk the same 2MB source
// tile together -> g reads mostly L2-hit. Drift is bounded by imbalance;
// correctness never depends on the rotation. Next tile's rs2 segment
// bounds prefetched under current tile's sums.
// MODE 0: conv -> tanh -> @W+b -> *dinv -> gout (stride 16, GT)
// MODE 1: conv -> tanh -> acc (f32, stride 12)
template<typename GT, int MODE>
__global__ void __launch_bounds__(256)
k_gather_rot(const int* __restrict__ rs2, const int* __restrict__ src,
             const float* __restrict__ dinv, const GT* __restrict__ gin,
             const void* __restrict__ W, const void* __restrict__ b,
             const int* __restrict__ flags, void* __restrict__ outp,
             int n, int nt){
  __shared__ float Ws[EMB*EMB];
  __shared__ float bs[EMB];
  int t = threadIdx.x;
  if (MODE == 0){
    int isbf = flags[1];
    if (t < EMB*EMB) Ws[t] = ldf(W, t, isbf);
    if (t < EMB)     bs[t] = ldf(b, t, isbf);
    __syncthreads();
  }
  int c0 = blockIdx.x*512 + t;
  int c1 = c0 + 256;
  bool v0 = (c0 < n), v1 = (c1 < n);
  int q0 = v0 ? c0 : 0, q1 = v1 ? c1 : 0;
  int base0 = ((q0>>BSHIFT)<<12) + (q0 & (BSPAN-1));
  int base1 = ((q1>>BSHIFT)<<12) + (q1 & (BSPAN-1));
  float a0[12], a1[12];
  #pragma unroll
  for (int j=0;j<12;j++){ a0[j]=0.f; a1[j]=0.f; }
  int tau = (int)(blockIdx.x & 7) % nt;
  int i0 = base0 + (tau<<BSHIFT);
  int i1 = base1 + (tau<<BSHIFT);
  int s0 = rs2[i0], e0 = rs2[i0+1];
  int s1 = rs2[i1], e1 = rs2[i1+1];
  for (int k=0; k<nt; k++){
    int tn = tau+1; if (tn >= nt) tn = 0;
    int ps0=0, pe0=0, ps1=0, pe1=0;
    if (k+1 < nt){
      int ni0 = base0 + (tn<<BSHIFT);
      int ni1 = base1 + (tn<<BSHIFT);
      ps0 = rs2[ni0]; pe0 = rs2[ni0+1];
      ps1 = rs2[ni1]; pe1 = rs2[ni1+1];
    }
    seg_sum2<GT>(gin, src, s0, e0, s1, e1, a0, a1);
    s0=ps0; e0=pe0; s1=ps1; e1=pe1; tau=tn;
  }
  finish_col<GT,MODE>(c0, n, a0, gin, dinv, Ws, bs, outp);
  finish_col<GT,MODE>(c1, n, a1, gin, dinv, Ws, bs, outp);
}

// ---- FALLBACK (small ws): atomic scatter path ----------------------------
__global__ void k_cnt_deg(const int* __restrict__ ei, const int* __restrict__ flags,
                          int* __restrict__ cnt, int e){
  int i = blockIdx.x*blockDim.x + threadIdx.x;
  if (i >= e) return;
  atomicAdd(&cnt[ld_col(ei, e, i, flags[0])], 1);
}
__global__ void k_dinv_from_cnt(const int* __restrict__ cnt, float* __restrict__ dinv, int n){
  int i = blockIdx.x*blockDim.x + threadIdx.x;
  if (i < n) dinv[i] = rsqrtf((float)(cnt[i] + 1));
}
__global__ void k_selfinit(const float* __restrict__ g, const float* __restrict__ dinv,
                           float* __restrict__ acc, int n){
  int i = blockIdx.x*blockDim.x + threadIdx.x;
  if (i >= n) return;
  float d = dinv[i];
  float h[12]; rowload(g + (size_t)i*16, h);
  #pragma unroll
  for (int j=0;j<EMB;j++) acc[(size_t)i*EMB+j] = d*h[j];
}
__global__ void k_scatter(const int* __restrict__ ei, const int* __restrict__ flags,
                          const float* __restrict__ dinv, const float* __restrict__ g,
                          float* __restrict__ acc, int e){
  int i = blockIdx.x*blockDim.x + threadIdx.x;
  if (i >= e) return;
  int w64 = flags[0];
  int r = ld_row(ei, e, i, w64);
  int c = ld_col(ei, e, i, w64);
  float w = dinv[c];
  float h[12];
  rowload(g + (size_t)r*16, h);
  float* ap = acc + (size_t)c*EMB;
  #pragma unroll
  for (int j=0;j<EMB;j++) atomicAdd(ap+j, w*h[j]);
}

// ---- pooling + output head ----------------------------------------------
template<int DOTANH>
__global__ void __launch_bounds__(256)
k_pool(const float* __restrict__ acc, const int* __restrict__ batch,
       const int* __restrict__ flags,
       const void* __restrict__ Wout, const void* __restrict__ bout,
       void* __restrict__ out, int n){
  int g = blockIdx.x;
  int w64  = flags[0];
  int isbf = flags[1];
  __shared__ int se[2];
  __shared__ float smax[4][EMB];
  __shared__ float ssum[4][EMB];
  __shared__ float hid[2*EMB];
  if (threadIdx.x == 0){
    int lo=0, hi=n;
    while (lo<hi){ int m=(lo+hi)>>1; if (ld_batch(batch,m,w64) < g) lo=m+1; else hi=m; }
    se[0]=lo;
    int lo2=lo; hi=n;
    while (lo2<hi){ int m=(lo2+hi)>>1; if (ld_batch(batch,m,w64) < g+1) lo2=m+1; else hi=m; }
    se[1]=lo2;
  }
  __syncthreads();
  int start=se[0], end=se[1];
  float lmax[EMB], lsum[EMB];
  #pragma unroll
  for (int j=0;j<EMB;j++){ lmax[j]=-3.0e38f; lsum[j]=0.f; }
  for (int i=start+(int)threadIdx.x; i<end; i+=blockDim.x){
    size_t base=(size_t)i*EMB;
    #pragma unroll
    for (int j=0;j<EMB;j++){
      float h = DOTANH ? tanhf(acc[base+j]) : acc[base+j];
      lmax[j] = fmaxf(lmax[j], h);
      lsum[j] += h;
    }
  }
  #pragma unroll
  for (int m=32;m>=1;m>>=1){
    #pragma unroll
    for (int j=0;j<EMB;j++){
      lmax[j] = fmaxf(lmax[j], __shfl_xor(lmax[j], m, 64));
      lsum[j] += __shfl_xor(lsum[j], m, 64);
    }
  }
  int wave = threadIdx.x>>6, lane = threadIdx.x&63;
  if (lane==0){
    #pragma unroll
    for (int j=0;j<EMB;j++){ smax[wave][j]=lmax[j]; ssum[wave][j]=lsum[j]; }
  }
  __syncthreads();
  int cnt = end-start;
  if (threadIdx.x < EMB){
    int j = threadIdx.x;
    float mx=smax[0][j], sm=ssum[0][j];
    #pragma unroll
    for (int w=1;w<4;w++){ mx=fmaxf(mx,smax[w][j]); sm+=ssum[w][j]; }
    if (cnt <= 0){ mx = 0.f; sm = 0.f; }
    float mean = sm / fmaxf((float)cnt, 1.0f);
    hid[j]     = mx;
    hid[EMB+j] = mean;
    stout(out, (size_t)NG*NCLS + (size_t)g*2*EMB + j,       mx,   isbf);
    stout(out, (size_t)NG*NCLS + (size_t)g*2*EMB + EMB + j, mean, isbf);
  }
  __syncthreads();
  if (threadIdx.x < NCLS){
    int c = threadIdx.x;
    float o = ldf(bout, c, isbf);
    #pragma unroll
    for (int k=0;k<2*EMB;k++) o = fmaf(hid[k], ldf(Wout, (size_t)k*NCLS+c, isbf), o);
    stout(out, (size_t)g*NCLS + c, o, isbf);
  }
}

__global__ void k_zero_out_noflags(void* __restrict__ out, int m){
  int i = blockIdx.x*blockDim.x + threadIdx.x;
  if (i < m) ((float*)out)[i] = 0.0f;
}

// ---- CSR build (shared) --------------------------------------------------
static void build_csr(const int* ei, const void* x, int* flags, int* bcnt, int* bbase,
                      int* bofs, float* dinv, int* src, int* pairs, int* rs2,
                      int N, int E, int NB, hipStream_t stream){
  const int TB = 256;
  const int gc = (E + CHUNK - 1) / CHUNK;
  const int NBK = NB * NKEY;
  k_detect      <<<1, 64, 0, stream>>>(ei, (const unsigned short*)x, flags);
  k_zero_i      <<<(NB+TB-1)/TB, TB, 0, stream>>>(bcnt, NB);
  k_bkt_count   <<<gc, TB, 0, stream>>>(ei, flags, bcnt, bofs, E, NB);
  k_bkt_scan_par<<<1, 1024, 0, stream>>>(bcnt, bbase, rs2, NB, NBK);
  k_colscan     <<<NB, TB, 0, stream>>>(bofs, bbase, NB, gc);
  k_bkt_place   <<<gc, TB, 0, stream>>>(ei, flags, bofs, pairs, E, NB);
  k_group       <<<NB, TB, 0, stream>>>(pairs, bbase, dinv, src, rs2, N);
}

static size_t alignup(size_t v){ return (v + 63) & ~(size_t)63; }
static size_t maxsz(size_t a, size_t b){ return a > b ? a : b; }

extern "C" void kernel_launch(void* const* d_in, const int* in_sizes, int n_in,
                              void* d_out, int out_size, void* d_ws, size_t ws_size,
                              hipStream_t stream) {
  const void* x     = d_in[0];
  const int*  ei    = (const int*)d_in[1];
  const int*  batch = (const int*)d_in[2];
  const void* W0 = d_in[3];  const void* b0 = d_in[4];
  const void* W1 = d_in[5];  const void* b1 = d_in[6];
  const void* W2 = d_in[7];  const void* b2 = d_in[8];
  const void* W3 = d_in[9];  const void* b3 = d_in[10];
  const void* Wout = d_in[11]; const void* bout = d_in[12];

  const int N = in_sizes[0] / 4;
  const int E = in_sizes[1] / 2;
  const int NB = (N + BSPAN - 1) >> BSHIFT;
  const int GC = (E + CHUNK - 1) / CHUNK;
  const int TB = 256;
  const int gn = (N + TB - 1) / TB;
  const int gr = (N + 511) / 512;     // rotated gather grid (2 cols/thread)
  const int nt = (N + (1<<TSHIFT) - 1) >> TSHIFT;

  char* base = (char*)d_ws;

  size_t o_flags  = 0;
  size_t o_dinv   = alignup(o_flags + 64);
  size_t o_bcnt   = alignup(o_dinv + (size_t)N*4);
  size_t o_bbase  = alignup(o_bcnt + (size_t)NB*4);
  size_t o_bofs   = alignup(o_bbase + ((size_t)NB+1)*4);
  size_t o_rs2    = alignup(o_bofs + (size_t)GC*NB*4);
  size_t o_src    = alignup(o_rs2 + ((size_t)NB*NKEY + 1)*4);
  size_t o_buf    = alignup(o_src + (size_t)E*4);     // pairs aliases from here

  int* flags  = (int*)(base+o_flags);
  float* dinv = (float*)(base+o_dinv);
  int* bcnt   = (int*)(base+o_bcnt);
  int* bbase  = (int*)(base+o_bbase);
  int* bofs   = (int*)(base+o_bofs);
  int* rs2    = (int*)(base+o_rs2);
  int* src    = (int*)(base+o_src);
  int* pairs  = (int*)(base+o_buf);

  bool fast_ok = (N < (1<<19)) && (NB <= MAXNB) && (nt <= NTILE);

  // T1: rotated-tile gather, bf16 g double-buffered. acc aliases R0.
  {
    size_t szR0 = maxsz((size_t)N*16*2, (size_t)N*EMB*4);
    size_t o_gB = alignup(o_buf + szR0);
    size_t need = o_gB + (size_t)N*16*2;
    bool pairs_fit = (size_t)E*4 <= need - o_buf;
    if (fast_ok && pairs_fit && ws_size >= need){
      bf16*  gA  = (bf16*)(base+o_buf);
      bf16*  gB  = (bf16*)(base+o_gB);
      float* acc = (float*)(base+o_buf);
      build_csr(ei, x, flags, bcnt, bbase, bofs, dinv, src, pairs, rs2, N, E, NB, stream);
      k_lin_first<bf16><<<gn, TB, 0, stream>>>(x, W0, b0, flags, dinv, gA, N);
      k_gather_rot<bf16,0><<<gr, TB, 0, stream>>>(rs2, src, dinv, gA, W1, b1, flags, gB, N, nt);
      k_gather_rot<bf16,0><<<gr, TB, 0, stream>>>(rs2, src, dinv, gB, W2, b2, flags, gA, N, nt);
      k_gather_rot<bf16,0><<<gr, TB, 0, stream>>>(rs2, src, dinv, gA, W3, b3, flags, gB, N, nt);
      k_gather_rot<bf16,1><<<gr, TB, 0, stream>>>(rs2, src, dinv, gB, 0, 0, flags, acc, N, nt);
      k_pool<0><<<NG, 256, 0, stream>>>(acc, batch, flags, Wout, bout, d_out, N);
      return;
    }
  }

  // T2: rotated-tile gather, f32 g double-buffered. acc aliases gA.
  {
    size_t o_gA = o_buf;
    size_t o_gB = alignup(o_gA + (size_t)N*16*4);
    size_t need = o_gB + (size_t)N*16*4;
    bool pairs_fit = (size_t)E*4 <= need - o_buf;
    if (fast_ok && pairs_fit && ws_size >= need){
      float* gA  = (float*)(base+o_gA);
      float* gB  = (float*)(base+o_gB);
      float* acc = gA;
      build_csr(ei, x, flags, bcnt, bbase, bofs, dinv, src, pairs, rs2, N, E, NB, stream);
      k_lin_first<float><<<gn, TB, 0, stream>>>(x, W0, b0, flags, dinv, gA, N);
      k_gather_rot<float,0><<<gr, TB, 0, stream>>>(rs2, src, dinv, gA, W1, b1, flags, gB, N, nt);
      k_gather_rot<float,0><<<gr, TB, 0, stream>>>(rs2, src, dinv, gB, W2, b2, flags, gA, N, nt);
      k_gather_rot<float,0><<<gr, TB, 0, stream>>>(rs2, src, dinv, gA, W3, b3, flags, gB, N, nt);
      k_gather_rot<float,1><<<gr, TB, 0, stream>>>(rs2, src, dinv, gB, 0, 0, flags, acc, N, nt);
      k_pool<0><<<NG, 256, 0, stream>>>(acc, batch, flags, Wout, bout, d_out, N);
      return;
    }
  }

  // T4: atomic-scatter fallback
  {
    size_t f_cnt  = alignup(o_dinv + (size_t)N*4);
    size_t f_g    = alignup(f_cnt + (size_t)N*4);
    size_t f_acc  = alignup(f_g + (size_t)N*16*4);
    size_t f_end  = f_acc + (size_t)N*EMB*4;
    const int ge = (E + TB - 1) / TB;
    int* cnt = (int*)(base+f_cnt);

    if (ws_size >= f_end){
      float* g   = (float*)(base+f_g);
      float* acc = (float*)(base+f_acc);
      k_detect  <<<1, 64, 0, stream>>>(ei, (const unsigned short*)x, flags);
      k_zero_i  <<<gn, TB, 0, stream>>>(cnt, N);
      k_cnt_deg <<<ge, TB, 0, stream>>>(ei, flags, cnt, E);
      k_dinv_from_cnt<<<gn, TB, 0, stream>>>(cnt, dinv, N);
      k_lin_first<float><<<gn, TB, 0, stream>>>(x, W0, b0, flags, dinv, g, N);
      k_selfinit <<<gn, TB, 0, stream>>>(g, dinv, acc, N);
      k_scatter  <<<ge, TB, 0, stream>>>(ei, flags, dinv, g, acc, E);
      const void* Wl[3] = {W1,W2,W3};
      const void* bl[3] = {b1,b2,b3};
      for (int l=0;l<3;l++){
        k_lin_mid<float><<<gn, TB, 0, stream>>>(acc, Wl[l], bl[l], flags, dinv, g, N);
        k_selfinit<<<gn, TB, 0, stream>>>(g, dinv, acc, N);
        k_scatter <<<ge, TB, 0, stream>>>(ei, flags, dinv, g, acc, E);
      }
      k_pool<1><<<NG, 256, 0, stream>>>(acc, batch, flags, Wout, bout, d_out, N);
    } else {
      k_zero_out_noflags<<<(out_size+255)/256, 256, 0, stream>>>(d_out, out_size);
    }
  }
}

// Round 5
// 553.473 us; speedup vs baseline: 8.2157x; 1.0857x over previous
//
#include <hip/hip_runtime.h>
#include <hip/hip_bf16.h>
#include <math.h>

typedef __hip_bfloat16 bf16;

#define EMB 12
#define NCLS 17
#define NG 1000
#define BSHIFT 9
#define BSPAN 512            // cols per bucket
#define MAXNB 1024           // max buckets (N <= 524287)
#define CHUNK 8192           // edges per block in count/place (= LDS stage cap)
#define EB 8                 // edge batch (MLP) in count/place
#define TSHIFT 16            // source tile = 65536 nodes = 2 MB bf16 (fits 4MB XCD L2)
#define NTILE 8              // max tiles (N < 2^19)
#define NKEY (BSPAN*NTILE)   // 4096 sort keys in k_group
#define SCAP 11264           // k_group LDS stage capacity (44 KB)

__device__ __forceinline__ float b2f(bf16 v){ return __bfloat162float(v); }

__device__ __forceinline__ unsigned short f2bf_rne(float f){
  unsigned int u = __float_as_uint(f);
  unsigned int r = (u + 0x7FFFu + ((u >> 16) & 1u)) >> 16;
  return (unsigned short)r;
}

__device__ __forceinline__ float ldf(const void* p, size_t i, int isbf){
  if (isbf) return b2f(((const bf16*)p)[i]);
  return ((const float*)p)[i];
}
__device__ __forceinline__ void stout(void* p, size_t i, float v, int isbf){
  if (isbf) ((unsigned short*)p)[i] = f2bf_rne(v);
  else      ((float*)p)[i] = v;
}

// ---- row load/store, stride 16 elements ----------------------------------
__device__ __forceinline__ void rowload(const float* p, float o[12]){
  const float4* q = (const float4*)p;
  float4 a = q[0], b = q[1], c = q[2];
  o[0]=a.x;o[1]=a.y;o[2]=a.z;o[3]=a.w;o[4]=b.x;o[5]=b.y;o[6]=b.z;o[7]=b.w;
  o[8]=c.x;o[9]=c.y;o[10]=c.z;o[11]=c.w;
}
__device__ __forceinline__ void rowload(const bf16* p, float o[12]){
  const uint4* q = (const uint4*)p;       // 32B row, 16B aligned
  uint4 u0 = q[0];
  uint2 u1 = *(const uint2*)(q+1);
  o[0] =__uint_as_float(u0.x<<16); o[1] =__uint_as_float(u0.x&0xFFFF0000u);
  o[2] =__uint_as_float(u0.y<<16); o[3] =__uint_as_float(u0.y&0xFFFF0000u);
  o[4] =__uint_as_float(u0.z<<16); o[5] =__uint_as_float(u0.z&0xFFFF0000u);
  o[6] =__uint_as_float(u0.w<<16); o[7] =__uint_as_float(u0.w&0xFFFF0000u);
  o[8] =__uint_as_float(u1.x<<16); o[9] =__uint_as_float(u1.x&0xFFFF0000u);
  o[10]=__uint_as_float(u1.y<<16); o[11]=__uint_as_float(u1.y&0xFFFF0000u);
}
__device__ __forceinline__ void rowstore(float* p, const float o[12]){
  float4* q = (float4*)p;
  q[0] = make_float4(o[0],o[1],o[2],o[3]);
  q[1] = make_float4(o[4],o[5],o[6],o[7]);
  q[2] = make_float4(o[8],o[9],o[10],o[11]);
}
__device__ __forceinline__ void rowstore(bf16* p, const float o[12]){
  unsigned int u[6];
  #pragma unroll
  for (int k=0;k<6;k++)
    u[k] = (unsigned int)f2bf_rne(o[2*k]) | ((unsigned int)f2bf_rne(o[2*k+1])<<16);
  uint2* q = (uint2*)p;
  q[0] = make_uint2(u[0],u[1]);
  q[1] = make_uint2(u[2],u[3]);
  q[2] = make_uint2(u[4],u[5]);
}

// ---- runtime dtype detection ---------------------------------------------
__global__ void k_detect(const int* __restrict__ ei, const unsigned short* __restrict__ xh,
                         int* __restrict__ flags){
  if (blockIdx.x==0 && threadIdx.x==0){
    int z = 1;
    for (int k=1; k<32; k+=2) z &= (ei[k]==0);
    flags[0] = z;
    int hits = 0;
    for (int k=0; k<32; k+=2){
      int e = (xh[k] >> 7) & 0xFF;
      if (e >= 100 && e <= 140) hits++;
    }
    flags[1] = (hits >= 12) ? 1 : 0;
  }
}
__device__ __forceinline__ int ld_row(const int* ei, long long E, long long i, int w64){
  return w64 ? ei[2*i] : ei[i];
}
__device__ __forceinline__ int ld_col(const int* ei, long long E, long long i, int w64){
  return w64 ? ei[2*E + 2*i] : ei[E + i];
}
__device__ __forceinline__ int ld_batch(const int* b, long long i, int w64){
  return w64 ? b[2*i] : b[i];
}

// ---- bucketed CSR build (no per-edge global atomics) ---------------------
__global__ void k_zero_i(int* __restrict__ p, int n){
  int i = blockIdx.x*blockDim.x + threadIdx.x;
  if (i < n) p[i] = 0;
}
// Pass A: per-block LDS histogram; writes per-block counts (bofs) + totals.
__global__ void __launch_bounds__(256)
k_bkt_count(const int* __restrict__ ei, const int* __restrict__ flags,
            int* __restrict__ bcnt, int* __restrict__ bofs, int E, int NB){
  __shared__ int h[MAXNB];
  int t = threadIdx.x;
  for (int j=t; j<NB; j+=256) h[j] = 0;
  __syncthreads();
  int w64 = flags[0];
  long long base = (long long)blockIdx.x * CHUNK;
  for (int k0=0; k0<CHUNK; k0+=256*EB){
    int c[EB]; bool v[EB];
    #pragma unroll
    for (int u=0;u<EB;u++){
      long long i = base + k0 + u*256 + t;
      v[u] = (i < E);
      c[u] = v[u] ? ld_col(ei, E, i, w64) : 0;
    }
    #pragma unroll
    for (int u=0;u<EB;u++) if (v[u]) atomicAdd(&h[c[u]>>BSHIFT], 1);
  }
  __syncthreads();
  size_t rowb = (size_t)blockIdx.x * NB;
  for (int j=t; j<NB; j+=256){
    int c = h[j];
    bofs[rowb + j] = c;
    if (c > 0) atomicAdd(&bcnt[j], c);
  }
}
// bucket-total scan (single block); also writes rs2 sentinel.
__global__ void __launch_bounds__(1024)
k_bkt_scan_par(const int* __restrict__ bcnt, int* __restrict__ bbase,
               int* __restrict__ rs2, int NB, int NBK){
  __shared__ int s[1024];
  int t = threadIdx.x;
  int v = (t < NB) ? bcnt[t] : 0;
  s[t] = v;
  __syncthreads();
  for (int off=1; off<1024; off<<=1){
    int add = (t >= off) ? s[t-off] : 0;
    __syncthreads();
    s[t] += add;
    __syncthreads();
  }
  if (t < NB) bbase[t] = s[t] - v;
  if (t == 1023){
    bbase[NB] = s[1023];
    rs2[NBK]  = s[1023];
  }
}
// column scan: bofs[i][j] -> exact placement base for (block i, bucket j)
__global__ void __launch_bounds__(256)
k_colscan(int* __restrict__ bofs, const int* __restrict__ bbase, int NB, int GC){
  __shared__ int part[256];
  int j = blockIdx.x, t = threadIdx.x;
  int K = (GC + 255) / 256;
  int beg = t*K, end = beg+K < GC ? beg+K : GC;
  int s = 0;
  for (int i=beg; i<end; i++) s += bofs[(size_t)i*NB + j];
  part[t] = s;
  __syncthreads();
  for (int off=1; off<256; off<<=1){
    int add = (t >= off) ? part[t-off] : 0;
    __syncthreads();
    part[t] += add;
    __syncthreads();
  }
  int run = bbase[j] + part[t] - s;
  for (int i=beg; i<end; i++){
    size_t idx = (size_t)i*NB + j;
    int v = bofs[idx];
    bofs[idx] = run;
    run += v;
  }
}
// Pass C: place packed (coloff<<22 | tile<<19 | row) via LDS sort-then-flush.
// Local histogram + scan -> LDS scatter sorted by bucket with precomputed
// global dest -> linear flush (consecutive lanes hit consecutive-ish lines).
__global__ void __launch_bounds__(256)
k_bkt_place(const int* __restrict__ ei, const int* __restrict__ flags,
            const int* __restrict__ bofs, int* __restrict__ pairs, int E, int NB){
  __shared__ int hb[MAXNB];     // 4 KB: global base (adjusted by -lbase)
  __shared__ int lcur[MAXNB];   // 4 KB: local count -> local cursor
  __shared__ int part[256];     // 1 KB
  __shared__ int vals[CHUNK];   // 32 KB
  __shared__ int dst[CHUNK];    // 32 KB   total ~73 KB -> 2 blocks/CU
  int t = threadIdx.x;
  size_t rowb = (size_t)blockIdx.x * NB;
  for (int j=t; j<NB; j+=256){ hb[j] = bofs[rowb + j]; lcur[j] = 0; }
  __syncthreads();
  int w64 = flags[0];
  long long base = (long long)blockIdx.x * CHUNK;
  long long rem = E - base;
  int total = (rem < CHUNK) ? (int)rem : CHUNK;
  // pass 1: local histogram
  for (int k0=0; k0<CHUNK; k0+=256*EB){
    int c[EB]; bool v[EB];
    #pragma unroll
    for (int u=0;u<EB;u++){
      long long i = base + k0 + u*256 + t;
      v[u] = (i < E);
      c[u] = v[u] ? ld_col(ei, E, i, w64) : 0;
    }
    #pragma unroll
    for (int u=0;u<EB;u++) if (v[u]) atomicAdd(&lcur[c[u]>>BSHIFT], 1);
  }
  __syncthreads();
  // scan: lcur -> exclusive local base; hb[j] -= base so dest = hb[j] + p
  int loc[4]; int s = 0;
  #pragma unroll
  for (int u=0;u<4;u++){ int j=t*4+u; loc[u] = (j<NB) ? lcur[j] : 0; s += loc[u]; }
  part[t] = s;
  __syncthreads();
  for (int off=1; off<256; off<<=1){
    int add = (t >= off) ? part[t-off] : 0;
    __syncthreads();
    part[t] += add;
    __syncthreads();
  }
  int run = part[t] - s;
  #pragma unroll
  for (int u=0;u<4;u++){
    int j=t*4+u;
    if (j<NB){ lcur[j] = run; hb[j] -= run; }
    run += loc[u];
  }
  __syncthreads();
  // pass 2: re-read edges (L2-warm), scatter into LDS sorted by bucket
  for (int k0=0; k0<CHUNK; k0+=256*EB){
    int r[EB], c[EB]; bool v[EB];
    #pragma unroll
    for (int u=0;u<EB;u++){
      long long i = base + k0 + u*256 + t;
      v[u] = (i < E);
      r[u] = v[u] ? ld_row(ei, E, i, w64) : 0;
      c[u] = v[u] ? ld_col(ei, E, i, w64) : 0;
    }
    #pragma unroll
    for (int u=0;u<EB;u++){
      if (v[u]){
        int j = c[u]>>BSHIFT;
        int p = atomicAdd(&lcur[j], 1);
        vals[p] = r[u] | ((r[u]>>TSHIFT)<<19) | ((c[u] & (BSPAN-1)) << 22);
        dst[p]  = hb[j] + p;
      }
    }
  }
  __syncthreads();
  for (int s2=t; s2<total; s2+=256) pairs[dst[s2]] = vals[s2];
}
// key = (tile, coloff) -> tile-major order within bucket
__device__ __forceinline__ int tkey(int pk){
  return (((pk>>19)&7)<<BSHIFT) | (pk>>22);
}
// Pass D: one block per bucket — sort by (tile, col); dump rs2 segment
// starts; emit src rows via LDS stage (coalesced flush); dinv per col.
__global__ void __launch_bounds__(256)
k_group(const int* __restrict__ pairs, const int* __restrict__ bbase,
        float* __restrict__ dinv, int* __restrict__ src,
        int* __restrict__ rs2, int N){
  __shared__ int cnt[NKEY];    // 16 KB
  __shared__ int cur[NKEY];    // 16 KB
  __shared__ int part[256];    // 1 KB
  __shared__ int stage[SCAP];  // 44 KB   total ~77 KB -> 2 blocks/CU
  int b = blockIdx.x, t = threadIdx.x;
  int lo = bbase[b], hi = bbase[b+1];
  int cap = hi - lo;
  #pragma unroll
  for (int u=0;u<NKEY/256;u++) cnt[u*256+t] = 0;
  __syncthreads();
  {
    int p = lo + t;
    for (; p + 3*256 < hi; p += 4*256){
      int k0=tkey(pairs[p]), k1=tkey(pairs[p+256]), k2=tkey(pairs[p+512]), k3=tkey(pairs[p+768]);
      atomicAdd(&cnt[k0],1); atomicAdd(&cnt[k1],1);
      atomicAdd(&cnt[k2],1); atomicAdd(&cnt[k3],1);
    }
    for (; p < hi; p += 256) atomicAdd(&cnt[tkey(pairs[p])],1);
  }
  __syncthreads();
  int loc[16]; int s = 0;
  #pragma unroll
  for (int u=0;u<16;u++){ loc[u] = cnt[t*16+u]; s += loc[u]; }
  part[t] = s;
  __syncthreads();
  for (int off=1; off<256; off<<=1){
    int add = (t >= off) ? part[t-off] : 0;
    __syncthreads();
    part[t] += add;
    __syncthreads();
  }
  int run = lo + part[t] - s;
  #pragma unroll
  for (int u=0;u<16;u++){ cur[t*16+u] = run; run += loc[u]; }
  __syncthreads();
  // dump segment starts + dinv (cur still pristine here)
  {
    size_t rb = (size_t)b * NKEY;
    #pragma unroll
    for (int u=0;u<16;u++){ int k = t*16+u; rs2[rb + k] = cur[k]; }
    int col0 = b << BSHIFT;
    #pragma unroll
    for (int u=0;u<2;u++){
      int j = 2*t + u;
      int colg = col0 + j;
      if (colg < N){
        int deg = 0;
        #pragma unroll
        for (int tt=0; tt<NTILE; tt++) deg += cnt[(tt<<BSHIFT) | j];
        dinv[colg] = rsqrtf((float)deg + 1.0f);
      }
    }
  }
  __syncthreads();
  if (cap <= SCAP){
    // staged scatter: local pos = global pos - lo; flush coalesced
    int p = lo + t;
    for (; p + 3*256 < hi; p += 4*256){
      int pk0=pairs[p], pk1=pairs[p+256], pk2=pairs[p+512], pk3=pairs[p+768];
      int q0 = atomicAdd(&cur[tkey(pk0)], 1);
      int q1 = atomicAdd(&cur[tkey(pk1)], 1);
      int q2 = atomicAdd(&cur[tkey(pk2)], 1);
      int q3 = atomicAdd(&cur[tkey(pk3)], 1);
      stage[q0-lo] = pk0 & 0x7FFFF; stage[q1-lo] = pk1 & 0x7FFFF;
      stage[q2-lo] = pk2 & 0x7FFFF; stage[q3-lo] = pk3 & 0x7FFFF;
    }
    for (; p < hi; p += 256){
      int pk = pairs[p];
      int q = atomicAdd(&cur[tkey(pk)], 1);
      stage[q-lo] = pk & 0x7FFFF;
    }
    __syncthreads();
    for (int s2=t; s2<cap; s2+=256) src[lo+s2] = stage[s2];
  } else {
    // fallback: direct scatter (correctness for oversized buckets)
    int p = lo + t;
    for (; p + 3*256 < hi; p += 4*256){
      int pk0=pairs[p], pk1=pairs[p+256], pk2=pairs[p+512], pk3=pairs[p+768];
      int q0 = atomicAdd(&cur[tkey(pk0)], 1);
      int q1 = atomicAdd(&cur[tkey(pk1)], 1);
      int q2 = atomicAdd(&cur[tkey(pk2)], 1);
      int q3 = atomicAdd(&cur[tkey(pk3)], 1);
      src[q0] = pk0 & 0x7FFFF; src[q1] = pk1 & 0x7FFFF;
      src[q2] = pk2 & 0x7FFFF; src[q3] = pk3 & 0x7FFFF;
    }
    for (; p < hi; p += 256){
      int pk = pairs[p];
      int q = atomicAdd(&cur[tkey(pk)], 1);
      src[q] = pk & 0x7FFFF;
    }
  }
}

// ---- lin-first: g = dinv * (x @ W0 + b0), row stride 16 ------------------
template<typename GT>
__global__ void k_lin_first(const void* __restrict__ x, const void* __restrict__ W,
                            const void* __restrict__ b, const int* __restrict__ flags,
                            const float* __restrict__ dinv,
                            GT* __restrict__ g, int n){
  __shared__ float Ws[4*EMB];
  __shared__ float bs[EMB];
  int t = threadIdx.x;
  int isbf = flags[1];
  if (t < 4*EMB) Ws[t] = ldf(W, t, isbf);
  if (t < EMB)   bs[t] = ldf(b, t, isbf);
  __syncthreads();
  int i = blockIdx.x*blockDim.x + t;
  if (i >= n) return;
  float xi[4];
  #pragma unroll
  for (int k=0;k<4;k++) xi[k] = ldf(x, (size_t)i*4+k, isbf);
  float d = dinv[i];
  float o[12];
  #pragma unroll
  for (int j=0;j<EMB;j++){
    float h = bs[j];
    #pragma unroll
    for (int k=0;k<4;k++) h = fmaf(xi[k], Ws[k*EMB+j], h);
    o[j] = d*h;
  }
  rowstore(g + (size_t)i*16, o);
}

// ---- lin-mid (fallback path) ---------------------------------------------
template<typename GT>
__global__ void k_lin_mid(const float* __restrict__ acc, const void* __restrict__ W,
                          const void* __restrict__ b, const int* __restrict__ flags,
                          const float* __restrict__ dinv,
                          GT* __restrict__ g, int n){
  __shared__ float Ws[EMB*EMB];
  __shared__ float bs[EMB];
  int t = threadIdx.x;
  int isbf = flags[1];
  if (t < EMB*EMB) Ws[t] = ldf(W, t, isbf);
  if (t < EMB)     bs[t] = ldf(b, t, isbf);
  __syncthreads();
  int i = blockIdx.x*blockDim.x + t;
  if (i >= n) return;
  float xi[EMB];
  size_t abase = (size_t)i*EMB;
  #pragma unroll
  for (int k=0;k<EMB;k++) xi[k] = tanhf(acc[abase+k]);
  float d = dinv[i];
  float o[12];
  #pragma unroll
  for (int j=0;j<EMB;j++){
    float h = bs[j];
    #pragma unroll
    for (int k=0;k<EMB;k++) h = fmaf(xi[k], Ws[k*EMB+j], h);
    o[j] = d*h;
  }
  rowstore(g + (size_t)i*16, o);
}

// ---- segment tail: add rows src[p..e) into a[12], 2x unroll --------------
template<typename GT>
__device__ __forceinline__ void seg_tail(const GT* __restrict__ gin,
                                         const int* __restrict__ src,
                                         int p, int e, float a[12]){
  for (; p+1 < e; p += 2){
    int r0 = src[p], r1 = src[p+1];
    float h0[12], h1[12];
    rowload(gin + (size_t)r0*16, h0);
    rowload(gin + (size_t)r1*16, h1);
    #pragma unroll
    for (int j=0;j<12;j++) a[j] += h0[j] + h1[j];
  }
  if (p < e){
    int r = src[p];
    float h[12];
    rowload(gin + (size_t)r*16, h);
    #pragma unroll
    for (int j=0;j<12;j++) a[j] += h[j];
  }
}

// ---- dual segment sum: interleave two columns' segments (4 rows in flight)
template<typename GT>
__device__ __forceinline__ void seg_sum2(const GT* __restrict__ gin,
                                         const int* __restrict__ src,
                                         int p0, int e0, int p1, int e1,
                                         float a0[12], float a1[12]){
  while (p0+1 < e0 && p1+1 < e1){
    int r00 = src[p0], r01 = src[p0+1], r10 = src[p1], r11 = src[p1+1];
    float h00[12], h01[12], h10[12], h11[12];
    rowload(gin + (size_t)r00*16, h00);
    rowload(gin + (size_t)r01*16, h01);
    rowload(gin + (size_t)r10*16, h10);
    rowload(gin + (size_t)r11*16, h11);
    #pragma unroll
    for (int j=0;j<12;j++){ a0[j] += h00[j]+h01[j]; a1[j] += h10[j]+h11[j]; }
    p0 += 2; p1 += 2;
  }
  seg_tail<GT>(gin, src, p0, e0, a0);
  seg_tail<GT>(gin, src, p1, e1, a1);
}

// ---- epilogue: self-loop + tanh (+MLP) + store ---------------------------
template<typename GT, int MODE>
__device__ __forceinline__ void finish_col(int c, int n, const float a[12],
                                           const GT* __restrict__ gin,
                                           const float* __restrict__ dinv,
                                           const float* Ws, const float* bs,
                                           void* __restrict__ outp){
  if (c >= n) return;
  float v[12];
  rowload(gin + (size_t)c*16, v);         // self-loop
  #pragma unroll
  for (int j=0;j<12;j++) v[j] += a[j];
  float d = dinv[c];
  if (MODE == 0){
    float h[12];
    #pragma unroll
    for (int k=0;k<12;k++) h[k] = tanhf(d*v[k]);
    float o[12];
    #pragma unroll
    for (int j=0;j<12;j++){
      float w = bs[j];
      #pragma unroll
      for (int k=0;k<12;k++) w = fmaf(h[k], Ws[k*EMB+j], w);
      o[j] = d*w;
    }
    rowstore((GT*)outp + (size_t)c*16, o);
  } else {
    float4* ap = (float4*)((float*)outp + (size_t)c*EMB);
    ap[0] = make_float4(tanhf(d*v[0]), tanhf(d*v[1]), tanhf(d*v[2]),  tanhf(d*v[3]));
    ap[1] = make_float4(tanhf(d*v[4]), tanhf(d*v[5]), tanhf(d*v[6]),  tanhf(d*v[7]));
    ap[2] = make_float4(tanhf(d*v[8]), tanhf(d*v[9]), tanhf(d*v[10]), tanhf(d*v[11]));
  }
}

// ---- XCD-rotated tile gather (no barriers) -------------------------------
// Block handles 512 adjacent cols (2/thread). Tile visit order rotates by
// blockIdx&7 (~XCD id): blocks sharing an XCD L2 walk the same 2MB source
// tile together -> g reads mostly L2-hit. Drift is bounded by imbalance;
// correctness never depends on the rotation. Next tile's rs2 segment
// bounds prefetched under current tile's sums.
// MODE 0: conv -> tanh -> @W+b -> *dinv -> gout (stride 16, GT)
// MODE 1: conv -> tanh -> acc (f32, stride 12)
template<typename GT, int MODE>
__global__ void __launch_bounds__(256)
k_gather_rot(const int* __restrict__ rs2, const int* __restrict__ src,
             const float* __restrict__ dinv, const GT* __restrict__ gin,
             const void* __restrict__ W, const void* __restrict__ b,
             const int* __restrict__ flags, void* __restrict__ outp,
             int n, int nt){
  __shared__ float Ws[EMB*EMB];
  __shared__ float bs[EMB];
  int t = threadIdx.x;
  if (MODE == 0){
    int isbf = flags[1];
    if (t < EMB*EMB) Ws[t] = ldf(W, t, isbf);
    if (t < EMB)     bs[t] = ldf(b, t, isbf);
    __syncthreads();
  }
  int c0 = blockIdx.x*512 + t;
  int c1 = c0 + 256;
  bool v0 = (c0 < n), v1 = (c1 < n);
  int q0 = v0 ? c0 : 0, q1 = v1 ? c1 : 0;
  int base0 = ((q0>>BSHIFT)<<12) + (q0 & (BSPAN-1));
  int base1 = ((q1>>BSHIFT)<<12) + (q1 & (BSPAN-1));
  float a0[12], a1[12];
  #pragma unroll
  for (int j=0;j<12;j++){ a0[j]=0.f; a1[j]=0.f; }
  int tau = (int)(blockIdx.x & 7) % nt;
  int i0 = base0 + (tau<<BSHIFT);
  int i1 = base1 + (tau<<BSHIFT);
  int s0 = rs2[i0], e0 = rs2[i0+1];
  int s1 = rs2[i1], e1 = rs2[i1+1];
  for (int k=0; k<nt; k++){
    int tn = tau+1; if (tn >= nt) tn = 0;
    int ps0=0, pe0=0, ps1=0, pe1=0;
    if (k+1 < nt){
      int ni0 = base0 + (tn<<BSHIFT);
      int ni1 = base1 + (tn<<BSHIFT);
      ps0 = rs2[ni0]; pe0 = rs2[ni0+1];
      ps1 = rs2[ni1]; pe1 = rs2[ni1+1];
    }
    seg_sum2<GT>(gin, src, s0, e0, s1, e1, a0, a1);
    s0=ps0; e0=pe0; s1=ps1; e1=pe1; tau=tn;
  }
  finish_col<GT,MODE>(c0, n, a0, gin, dinv, Ws, bs, outp);
  finish_col<GT,MODE>(c1, n, a1, gin, dinv, Ws, bs, outp);
}

// ---- FALLBACK (small ws): atomic scatter path ----------------------------
__global__ void k_cnt_deg(const int* __restrict__ ei, const int* __restrict__ flags,
                          int* __restrict__ cnt, int e){
  int i = blockIdx.x*blockDim.x + threadIdx.x;
  if (i >= e) return;
  atomicAdd(&cnt[ld_col(ei, e, i, flags[0])], 1);
}
__global__ void k_dinv_from_cnt(const int* __restrict__ cnt, float* __restrict__ dinv, int n){
  int i = blockIdx.x*blockDim.x + threadIdx.x;
  if (i < n) dinv[i] = rsqrtf((float)(cnt[i] + 1));
}
__global__ void k_selfinit(const float* __restrict__ g, const float* __restrict__ dinv,
                           float* __restrict__ acc, int n){
  int i = blockIdx.x*blockDim.x + threadIdx.x;
  if (i >= n) return;
  float d = dinv[i];
  float h[12]; rowload(g + (size_t)i*16, h);
  #pragma unroll
  for (int j=0;j<EMB;j++) acc[(size_t)i*EMB+j] = d*h[j];
}
__global__ void k_scatter(const int* __restrict__ ei, const int* __restrict__ flags,
                          const float* __restrict__ dinv, const float* __restrict__ g,
                          float* __restrict__ acc, int e){
  int i = blockIdx.x*blockDim.x + threadIdx.x;
  if (i >= e) return;
  int w64 = flags[0];
  int r = ld_row(ei, e, i, w64);
  int c = ld_col(ei, e, i, w64);
  float w = dinv[c];
  float h[12];
  rowload(g + (size_t)r*16, h);
  float* ap = acc + (size_t)c*EMB;
  #pragma unroll
  for (int j=0;j<EMB;j++) atomicAdd(ap+j, w*h[j]);
}

// ---- pooling + output head ----------------------------------------------
template<int DOTANH>
__global__ void __launch_bounds__(256)
k_pool(const float* __restrict__ acc, const int* __restrict__ batch,
       const int* __restrict__ flags,
       const void* __restrict__ Wout, const void* __restrict__ bout,
       void* __restrict__ out, int n){
  int g = blockIdx.x;
  int w64  = flags[0];
  int isbf = flags[1];
  __shared__ int se[2];
  __shared__ float smax[4][EMB];
  __shared__ float ssum[4][EMB];
  __shared__ float hid[2*EMB];
  if (threadIdx.x == 0){
    int lo=0, hi=n;
    while (lo<hi){ int m=(lo+hi)>>1; if (ld_batch(batch,m,w64) < g) lo=m+1; else hi=m; }
    se[0]=lo;
    int lo2=lo; hi=n;
    while (lo2<hi){ int m=(lo2+hi)>>1; if (ld_batch(batch,m,w64) < g+1) lo2=m+1; else hi=m; }
    se[1]=lo2;
  }
  __syncthreads();
  int start=se[0], end=se[1];
  float lmax[EMB], lsum[EMB];
  #pragma unroll
  for (int j=0;j<EMB;j++){ lmax[j]=-3.0e38f; lsum[j]=0.f; }
  for (int i=start+(int)threadIdx.x; i<end; i+=blockDim.x){
    size_t base=(size_t)i*EMB;
    #pragma unroll
    for (int j=0;j<EMB;j++){
      float h = DOTANH ? tanhf(acc[base+j]) : acc[base+j];
      lmax[j] = fmaxf(lmax[j], h);
      lsum[j] += h;
    }
  }
  #pragma unroll
  for (int m=32;m>=1;m>>=1){
    #pragma unroll
    for (int j=0;j<EMB;j++){
      lmax[j] = fmaxf(lmax[j], __shfl_xor(lmax[j], m, 64));
      lsum[j] += __shfl_xor(lsum[j], m, 64);
    }
  }
  int wave = threadIdx.x>>6, lane = threadIdx.x&63;
  if (lane==0){
    #pragma unroll
    for (int j=0;j<EMB;j++){ smax[wave][j]=lmax[j]; ssum[wave][j]=lsum[j]; }
  }
  __syncthreads();
  int cnt = end-start;
  if (threadIdx.x < EMB){
    int j = threadIdx.x;
    float mx=smax[0][j], sm=ssum[0][j];
    #pragma unroll
    for (int w=1;w<4;w++){ mx=fmaxf(mx,smax[w][j]); sm+=ssum[w][j]; }
    if (cnt <= 0){ mx = 0.f; sm = 0.f; }
    float mean = sm / fmaxf((float)cnt, 1.0f);
    hid[j]     = mx;
    hid[EMB+j] = mean;
    stout(out, (size_t)NG*NCLS + (size_t)g*2*EMB + j,       mx,   isbf);
    stout(out, (size_t)NG*NCLS + (size_t)g*2*EMB + EMB + j, mean, isbf);
  }
  __syncthreads();
  if (threadIdx.x < NCLS){
    int c = threadIdx.x;
    float o = ldf(bout, c, isbf);
    #pragma unroll
    for (int k=0;k<2*EMB;k++) o = fmaf(hid[k], ldf(Wout, (size_t)k*NCLS+c, isbf), o);
    stout(out, (size_t)g*NCLS + c, o, isbf);
  }
}

__global__ void k_zero_out_noflags(void* __restrict__ out, int m){
  int i = blockIdx.x*blockDim.x + threadIdx.x;
  if (i < m) ((float*)out)[i] = 0.0f;
}

// ---- CSR build (shared) --------------------------------------------------
static void build_csr(const int* ei, const void* x, int* flags, int* bcnt, int* bbase,
                      int* bofs, float* dinv, int* src, int* pairs, int* rs2,
                      int N, int E, int NB, hipStream_t stream){
  const int TB = 256;
  const int gc = (E + CHUNK - 1) / CHUNK;
  const int NBK = NB * NKEY;
  k_detect      <<<1, 64, 0, stream>>>(ei, (const unsigned short*)x, flags);
  k_zero_i      <<<(NB+TB-1)/TB, TB, 0, stream>>>(bcnt, NB);
  k_bkt_count   <<<gc, TB, 0, stream>>>(ei, flags, bcnt, bofs, E, NB);
  k_bkt_scan_par<<<1, 1024, 0, stream>>>(bcnt, bbase, rs2, NB, NBK);
  k_colscan     <<<NB, TB, 0, stream>>>(bofs, bbase, NB, gc);
  k_bkt_place   <<<gc, TB, 0, stream>>>(ei, flags, bofs, pairs, E, NB);
  k_group       <<<NB, TB, 0, stream>>>(pairs, bbase, dinv, src, rs2, N);
}

static size_t alignup(size_t v){ return (v + 63) & ~(size_t)63; }
static size_t maxsz(size_t a, size_t b){ return a > b ? a : b; }

extern "C" void kernel_launch(void* const* d_in, const int* in_sizes, int n_in,
                              void* d_out, int out_size, void* d_ws, size_t ws_size,
                              hipStream_t stream) {
  const void* x     = d_in[0];
  const int*  ei    = (const int*)d_in[1];
  const int*  batch = (const int*)d_in[2];
  const void* W0 = d_in[3];  const void* b0 = d_in[4];
  const void* W1 = d_in[5];  const void* b1 = d_in[6];
  const void* W2 = d_in[7];  const void* b2 = d_in[8];
  const void* W3 = d_in[9];  const void* b3 = d_in[10];
  const void* Wout = d_in[11]; const void* bout = d_in[12];

  const int N = in_sizes[0] / 4;
  const int E = in_sizes[1] / 2;
  const int NB = (N + BSPAN - 1) >> BSHIFT;
  const int GC = (E + CHUNK - 1) / CHUNK;
  const int TB = 256;
  const int gn = (N + TB - 1) / TB;
  const int gr = (N + 511) / 512;     // rotated gather grid (2 cols/thread)
  const int nt = (N + (1<<TSHIFT) - 1) >> TSHIFT;

  char* base = (char*)d_ws;

  size_t o_flags  = 0;
  size_t o_dinv   = alignup(o_flags + 64);
  size_t o_bcnt   = alignup(o_dinv + (size_t)N*4);
  size_t o_bbase  = alignup(o_bcnt + (size_t)NB*4);
  size_t o_bofs   = alignup(o_bbase + ((size_t)NB+1)*4);
  size_t o_rs2    = alignup(o_bofs + (size_t)GC*NB*4);
  size_t o_src    = alignup(o_rs2 + ((size_t)NB*NKEY + 1)*4);
  size_t o_buf    = alignup(o_src + (size_t)E*4);     // pairs aliases from here

  int* flags  = (int*)(base+o_flags);
  float* dinv = (float*)(base+o_dinv);
  int* bcnt   = (int*)(base+o_bcnt);
  int* bbase  = (int*)(base+o_bbase);
  int* bofs   = (int*)(base+o_bofs);
  int* rs2    = (int*)(base+o_rs2);
  int* src    = (int*)(base+o_src);
  int* pairs  = (int*)(base+o_buf);

  bool fast_ok = (N < (1<<19)) && (NB <= MAXNB) && (nt <= NTILE);

  // T1: rotated-tile gather, bf16 g double-buffered. acc aliases R0.
  {
    size_t szR0 = maxsz((size_t)N*16*2, (size_t)N*EMB*4);
    size_t o_gB = alignup(o_buf + szR0);
    size_t need = o_gB + (size_t)N*16*2;
    bool pairs_fit = (size_t)E*4 <= need - o_buf;
    if (fast_ok && pairs_fit && ws_size >= need){
      bf16*  gA  = (bf16*)(base+o_buf);
      bf16*  gB  = (bf16*)(base+o_gB);
      float* acc = (float*)(base+o_buf);
      build_csr(ei, x, flags, bcnt, bbase, bofs, dinv, src, pairs, rs2, N, E, NB, stream);
      k_lin_first<bf16><<<gn, TB, 0, stream>>>(x, W0, b0, flags, dinv, gA, N);
      k_gather_rot<bf16,0><<<gr, TB, 0, stream>>>(rs2, src, dinv, gA, W1, b1, flags, gB, N, nt);
      k_gather_rot<bf16,0><<<gr, TB, 0, stream>>>(rs2, src, dinv, gB, W2, b2, flags, gA, N, nt);
      k_gather_rot<bf16,0><<<gr, TB, 0, stream>>>(rs2, src, dinv, gA, W3, b3, flags, gB, N, nt);
      k_gather_rot<bf16,1><<<gr, TB, 0, stream>>>(rs2, src, dinv, gB, 0, 0, flags, acc, N, nt);
      k_pool<0><<<NG, 256, 0, stream>>>(acc, batch, flags, Wout, bout, d_out, N);
      return;
    }
  }

  // T2: rotated-tile gather, f32 g double-buffered. acc aliases gA.
  {
    size_t o_gA = o_buf;
    size_t o_gB = alignup(o_gA + (size_t)N*16*4);
    size_t need = o_gB + (size_t)N*16*4;
    bool pairs_fit = (size_t)E*4 <= need - o_buf;
    if (fast_ok && pairs_fit && ws_size >= need){
      float* gA  = (float*)(base+o_gA);
      float* gB  = (float*)(base+o_gB);
      float* acc = gA;
      build_csr(ei, x, flags, bcnt, bbase, bofs, dinv, src, pairs, rs2, N, E, NB, stream);
      k_lin_first<float><<<gn, TB, 0, stream>>>(x, W0, b0, flags, dinv, gA, N);
      k_gather_rot<float,0><<<gr, TB, 0, stream>>>(rs2, src, dinv, gA, W1, b1, flags, gB, N, nt);
      k_gather_rot<float,0><<<gr, TB, 0, stream>>>(rs2, src, dinv, gB, W2, b2, flags, gA, N, nt);
      k_gather_rot<float,0><<<gr, TB, 0, stream>>>(rs2, src, dinv, gA, W3, b3, flags, gB, N, nt);
      k_gather_rot<float,1><<<gr, TB, 0, stream>>>(rs2, src, dinv, gB, 0, 0, flags, acc, N, nt);
      k_pool<0><<<NG, 256, 0, stream>>>(acc, batch, flags, Wout, bout, d_out, N);
      return;
    }
  }

  // T4: atomic-scatter fallback
  {
    size_t f_cnt  = alignup(o_dinv + (size_t)N*4);
    size_t f_g    = alignup(f_cnt + (size_t)N*4);
    size_t f_acc  = alignup(f_g + (size_t)N*16*4);
    size_t f_end  = f_acc + (size_t)N*EMB*4;
    const int ge = (E + TB - 1) / TB;
    int* cnt = (int*)(base+f_cnt);

    if (ws_size >= f_end){
      float* g   = (float*)(base+f_g);
      float* acc = (float*)(base+f_acc);
      k_detect  <<<1, 64, 0, stream>>>(ei, (const unsigned short*)x, flags);
      k_zero_i  <<<gn, TB, 0, stream>>>(cnt, N);
      k_cnt_deg <<<ge, TB, 0, stream>>>(ei, flags, cnt, E);
      k_dinv_from_cnt<<<gn, TB, 0, stream>>>(cnt, dinv, N);
      k_lin_first<float><<<gn, TB, 0, stream>>>(x, W0, b0, flags, dinv, g, N);
      k_selfinit <<<gn, TB, 0, stream>>>(g, dinv, acc, N);
      k_scatter  <<<ge, TB, 0, stream>>>(ei, flags, dinv, g, acc, E);
      const void* Wl[3] = {W1,W2,W3};
      const void* bl[3] = {b1,b2,b3};
      for (int l=0;l<3;l++){
        k_lin_mid<float><<<gn, TB, 0, stream>>>(acc, Wl[l], bl[l], flags, dinv, g, N);
        k_selfinit<<<gn, TB, 0, stream>>>(g, dinv, acc, N);
        k_scatter <<<ge, TB, 0, stream>>>(ei, flags, dinv, g, acc, E);
      }
      k_pool<1><<<NG, 256, 0, stream>>>(acc, batch, flags, Wout, bout, d_out, N);
    } else {
      k_zero_out_noflags<<<(out_size+255)/256, 256, 0, stream>>>(d_out, out_size);
    }
  }
}

// Round 6
// 523.477 us; speedup vs baseline: 8.6865x; 1.0573x over previous
//
#include <hip/hip_runtime.h>
#include <hip/hip_bf16.h>
#include <math.h>

typedef __hip_bfloat16 bf16;

#define EMB 12
#define NCLS 17
#define NG 1000
#define BSHIFT 9
#define BSPAN 512            // cols per bucket
#define MAXNB 1024           // max buckets (N <= 524287)
#define CHUNK 8192           // edges per block in count/place (= LDS stage cap)
#define EB 8                 // edge batch (MLP) in count/place
#define TSHIFT 16            // source tile = 65536 nodes = 2 MB bf16 (fits 4MB XCD L2)
#define NTILE 8              // max tiles (N < 2^19)
#define NKEY (BSPAN*NTILE)   // 4096 sort keys in k_group
#define SCAP 11264           // k_group LDS stage capacity (44 KB)

__device__ __forceinline__ float b2f(bf16 v){ return __bfloat162float(v); }

__device__ __forceinline__ unsigned short f2bf_rne(float f){
  unsigned int u = __float_as_uint(f);
  unsigned int r = (u + 0x7FFFu + ((u >> 16) & 1u)) >> 16;
  return (unsigned short)r;
}

__device__ __forceinline__ float ldf(const void* p, size_t i, int isbf){
  if (isbf) return b2f(((const bf16*)p)[i]);
  return ((const float*)p)[i];
}
__device__ __forceinline__ void stout(void* p, size_t i, float v, int isbf){
  if (isbf) ((unsigned short*)p)[i] = f2bf_rne(v);
  else      ((float*)p)[i] = v;
}

// ---- row load/store, stride 16 elements ----------------------------------
__device__ __forceinline__ void rowload(const float* p, float o[12]){
  const float4* q = (const float4*)p;
  float4 a = q[0], b = q[1], c = q[2];
  o[0]=a.x;o[1]=a.y;o[2]=a.z;o[3]=a.w;o[4]=b.x;o[5]=b.y;o[6]=b.z;o[7]=b.w;
  o[8]=c.x;o[9]=c.y;o[10]=c.z;o[11]=c.w;
}
__device__ __forceinline__ void rowload(const bf16* p, float o[12]){
  const uint4* q = (const uint4*)p;       // 32B row, 16B aligned
  uint4 u0 = q[0];
  uint2 u1 = *(const uint2*)(q+1);
  o[0] =__uint_as_float(u0.x<<16); o[1] =__uint_as_float(u0.x&0xFFFF0000u);
  o[2] =__uint_as_float(u0.y<<16); o[3] =__uint_as_float(u0.y&0xFFFF0000u);
  o[4] =__uint_as_float(u0.z<<16); o[5] =__uint_as_float(u0.z&0xFFFF0000u);
  o[6] =__uint_as_float(u0.w<<16); o[7] =__uint_as_float(u0.w&0xFFFF0000u);
  o[8] =__uint_as_float(u1.x<<16); o[9] =__uint_as_float(u1.x&0xFFFF0000u);
  o[10]=__uint_as_float(u1.y<<16); o[11]=__uint_as_float(u1.y&0xFFFF0000u);
}
__device__ __forceinline__ void rowstore(float* p, const float o[12]){
  float4* q = (float4*)p;
  q[0] = make_float4(o[0],o[1],o[2],o[3]);
  q[1] = make_float4(o[4],o[5],o[6],o[7]);
  q[2] = make_float4(o[8],o[9],o[10],o[11]);
}
__device__ __forceinline__ void rowstore(bf16* p, const float o[12]){
  unsigned int u[6];
  #pragma unroll
  for (int k=0;k<6;k++)
    u[k] = (unsigned int)f2bf_rne(o[2*k]) | ((unsigned int)f2bf_rne(o[2*k+1])<<16);
  uint2* q = (uint2*)p;
  q[0] = make_uint2(u[0],u[1]);
  q[1] = make_uint2(u[2],u[3]);
  q[2] = make_uint2(u[4],u[5]);
}

// ---- runtime dtype detection ---------------------------------------------
__global__ void k_detect(const int* __restrict__ ei, const unsigned short* __restrict__ xh,
                         int* __restrict__ flags){
  if (blockIdx.x==0 && threadIdx.x==0){
    int z = 1;
    for (int k=1; k<32; k+=2) z &= (ei[k]==0);
    flags[0] = z;
    int hits = 0;
    for (int k=0; k<32; k+=2){
      int e = (xh[k] >> 7) & 0xFF;
      if (e >= 100 && e <= 140) hits++;
    }
    flags[1] = (hits >= 12) ? 1 : 0;
  }
}
__device__ __forceinline__ int ld_row(const int* ei, long long E, long long i, int w64){
  return w64 ? ei[2*i] : ei[i];
}
__device__ __forceinline__ int ld_col(const int* ei, long long E, long long i, int w64){
  return w64 ? ei[2*E + 2*i] : ei[E + i];
}
__device__ __forceinline__ int ld_batch(const int* b, long long i, int w64){
  return w64 ? b[2*i] : b[i];
}

// ---- bucketed CSR build (no per-edge global atomics) ---------------------
__global__ void k_zero_i(int* __restrict__ p, int n){
  int i = blockIdx.x*blockDim.x + threadIdx.x;
  if (i < n) p[i] = 0;
}
// Pass A: per-block LDS histogram; writes per-block counts (bofs) + totals.
__global__ void __launch_bounds__(256)
k_bkt_count(const int* __restrict__ ei, const int* __restrict__ flags,
            int* __restrict__ bcnt, int* __restrict__ bofs, int E, int NB){
  __shared__ int h[MAXNB];
  int t = threadIdx.x;
  for (int j=t; j<NB; j+=256) h[j] = 0;
  __syncthreads();
  int w64 = flags[0];
  long long base = (long long)blockIdx.x * CHUNK;
  for (int k0=0; k0<CHUNK; k0+=256*EB){
    int c[EB]; bool v[EB];
    #pragma unroll
    for (int u=0;u<EB;u++){
      long long i = base + k0 + u*256 + t;
      v[u] = (i < E);
      c[u] = v[u] ? ld_col(ei, E, i, w64) : 0;
    }
    #pragma unroll
    for (int u=0;u<EB;u++) if (v[u]) atomicAdd(&h[c[u]>>BSHIFT], 1);
  }
  __syncthreads();
  size_t rowb = (size_t)blockIdx.x * NB;
  for (int j=t; j<NB; j+=256){
    int c = h[j];
    bofs[rowb + j] = c;
    if (c > 0) atomicAdd(&bcnt[j], c);
  }
}
// bucket-total scan (single block); also writes rs2 sentinel.
__global__ void __launch_bounds__(1024)
k_bkt_scan_par(const int* __restrict__ bcnt, int* __restrict__ bbase,
               int* __restrict__ rs2, int NB, int NBK){
  __shared__ int s[1024];
  int t = threadIdx.x;
  int v = (t < NB) ? bcnt[t] : 0;
  s[t] = v;
  __syncthreads();
  for (int off=1; off<1024; off<<=1){
    int add = (t >= off) ? s[t-off] : 0;
    __syncthreads();
    s[t] += add;
    __syncthreads();
  }
  if (t < NB) bbase[t] = s[t] - v;
  if (t == 1023){
    bbase[NB] = s[1023];
    rs2[NBK]  = s[1023];
  }
}
// column scan: bofs[i][j] -> exact placement base for (block i, bucket j)
__global__ void __launch_bounds__(256)
k_colscan(int* __restrict__ bofs, const int* __restrict__ bbase, int NB, int GC){
  __shared__ int part[256];
  int j = blockIdx.x, t = threadIdx.x;
  int K = (GC + 255) / 256;
  int beg = t*K, end = beg+K < GC ? beg+K : GC;
  int s = 0;
  for (int i=beg; i<end; i++) s += bofs[(size_t)i*NB + j];
  part[t] = s;
  __syncthreads();
  for (int off=1; off<256; off<<=1){
    int add = (t >= off) ? part[t-off] : 0;
    __syncthreads();
    part[t] += add;
    __syncthreads();
  }
  int run = bbase[j] + part[t] - s;
  for (int i=beg; i<end; i++){
    size_t idx = (size_t)i*NB + j;
    int v = bofs[idx];
    bofs[idx] = run;
    run += v;
  }
}
// Pass C: place packed (coloff<<22 | tile<<19 | row) via LDS sort-then-flush.
__global__ void __launch_bounds__(256)
k_bkt_place(const int* __restrict__ ei, const int* __restrict__ flags,
            const int* __restrict__ bofs, int* __restrict__ pairs, int E, int NB){
  __shared__ int hb[MAXNB];     // 4 KB: global base (adjusted by -lbase)
  __shared__ int lcur[MAXNB];   // 4 KB: local count -> local cursor
  __shared__ int part[256];     // 1 KB
  __shared__ int vals[CHUNK];   // 32 KB
  __shared__ int dst[CHUNK];    // 32 KB   total ~73 KB -> 2 blocks/CU
  int t = threadIdx.x;
  size_t rowb = (size_t)blockIdx.x * NB;
  for (int j=t; j<NB; j+=256){ hb[j] = bofs[rowb + j]; lcur[j] = 0; }
  __syncthreads();
  int w64 = flags[0];
  long long base = (long long)blockIdx.x * CHUNK;
  long long rem = E - base;
  int total = (rem < CHUNK) ? (int)rem : CHUNK;
  // pass 1: local histogram
  for (int k0=0; k0<CHUNK; k0+=256*EB){
    int c[EB]; bool v[EB];
    #pragma unroll
    for (int u=0;u<EB;u++){
      long long i = base + k0 + u*256 + t;
      v[u] = (i < E);
      c[u] = v[u] ? ld_col(ei, E, i, w64) : 0;
    }
    #pragma unroll
    for (int u=0;u<EB;u++) if (v[u]) atomicAdd(&lcur[c[u]>>BSHIFT], 1);
  }
  __syncthreads();
  // scan: lcur -> exclusive local base; hb[j] -= base so dest = hb[j] + p
  int loc[4]; int s = 0;
  #pragma unroll
  for (int u=0;u<4;u++){ int j=t*4+u; loc[u] = (j<NB) ? lcur[j] : 0; s += loc[u]; }
  part[t] = s;
  __syncthreads();
  for (int off=1; off<256; off<<=1){
    int add = (t >= off) ? part[t-off] : 0;
    __syncthreads();
    part[t] += add;
    __syncthreads();
  }
  int run = part[t] - s;
  #pragma unroll
  for (int u=0;u<4;u++){
    int j=t*4+u;
    if (j<NB){ lcur[j] = run; hb[j] -= run; }
    run += loc[u];
  }
  __syncthreads();
  // pass 2: re-read edges (L2-warm), scatter into LDS sorted by bucket
  for (int k0=0; k0<CHUNK; k0+=256*EB){
    int r[EB], c[EB]; bool v[EB];
    #pragma unroll
    for (int u=0;u<EB;u++){
      long long i = base + k0 + u*256 + t;
      v[u] = (i < E);
      r[u] = v[u] ? ld_row(ei, E, i, w64) : 0;
      c[u] = v[u] ? ld_col(ei, E, i, w64) : 0;
    }
    #pragma unroll
    for (int u=0;u<EB;u++){
      if (v[u]){
        int j = c[u]>>BSHIFT;
        int p = atomicAdd(&lcur[j], 1);
        vals[p] = r[u] | ((r[u]>>TSHIFT)<<19) | ((c[u] & (BSPAN-1)) << 22);
        dst[p]  = hb[j] + p;
      }
    }
  }
  __syncthreads();
  for (int s2=t; s2<total; s2+=256) pairs[dst[s2]] = vals[s2];
}
// key = (tile, coloff) -> tile-major order within bucket
__device__ __forceinline__ int tkey(int pk){
  return (((pk>>19)&7)<<BSHIFT) | (pk>>22);
}
// Pass D: one block per bucket — sort by (tile, col); dump rs2 segment
// starts; emit src rows via LDS stage (coalesced flush); dinv per col.
__global__ void __launch_bounds__(256)
k_group(const int* __restrict__ pairs, const int* __restrict__ bbase,
        float* __restrict__ dinv, int* __restrict__ src,
        int* __restrict__ rs2, int N){
  __shared__ int cnt[NKEY];    // 16 KB
  __shared__ int cur[NKEY];    // 16 KB
  __shared__ int part[256];    // 1 KB
  __shared__ int stage[SCAP];  // 44 KB   total ~77 KB -> 2 blocks/CU
  int b = blockIdx.x, t = threadIdx.x;
  int lo = bbase[b], hi = bbase[b+1];
  int cap = hi - lo;
  #pragma unroll
  for (int u=0;u<NKEY/256;u++) cnt[u*256+t] = 0;
  __syncthreads();
  {
    int p = lo + t;
    for (; p + 3*256 < hi; p += 4*256){
      int k0=tkey(pairs[p]), k1=tkey(pairs[p+256]), k2=tkey(pairs[p+512]), k3=tkey(pairs[p+768]);
      atomicAdd(&cnt[k0],1); atomicAdd(&cnt[k1],1);
      atomicAdd(&cnt[k2],1); atomicAdd(&cnt[k3],1);
    }
    for (; p < hi; p += 256) atomicAdd(&cnt[tkey(pairs[p])],1);
  }
  __syncthreads();
  int loc[16]; int s = 0;
  #pragma unroll
  for (int u=0;u<16;u++){ loc[u] = cnt[t*16+u]; s += loc[u]; }
  part[t] = s;
  __syncthreads();
  for (int off=1; off<256; off<<=1){
    int add = (t >= off) ? part[t-off] : 0;
    __syncthreads();
    part[t] += add;
    __syncthreads();
  }
  int run = lo + part[t] - s;
  #pragma unroll
  for (int u=0;u<16;u++){ cur[t*16+u] = run; run += loc[u]; }
  __syncthreads();
  // dump segment starts + dinv (cur still pristine here)
  {
    size_t rb = (size_t)b * NKEY;
    #pragma unroll
    for (int u=0;u<16;u++){ int k = t*16+u; rs2[rb + k] = cur[k]; }
    int col0 = b << BSHIFT;
    #pragma unroll
    for (int u=0;u<2;u++){
      int j = 2*t + u;
      int colg = col0 + j;
      if (colg < N){
        int deg = 0;
        #pragma unroll
        for (int tt=0; tt<NTILE; tt++) deg += cnt[(tt<<BSHIFT) | j];
        dinv[colg] = rsqrtf((float)deg + 1.0f);
      }
    }
  }
  __syncthreads();
  if (cap <= SCAP){
    // staged scatter: local pos = global pos - lo; flush coalesced
    int p = lo + t;
    for (; p + 3*256 < hi; p += 4*256){
      int pk0=pairs[p], pk1=pairs[p+256], pk2=pairs[p+512], pk3=pairs[p+768];
      int q0 = atomicAdd(&cur[tkey(pk0)], 1);
      int q1 = atomicAdd(&cur[tkey(pk1)], 1);
      int q2 = atomicAdd(&cur[tkey(pk2)], 1);
      int q3 = atomicAdd(&cur[tkey(pk3)], 1);
      stage[q0-lo] = pk0 & 0x7FFFF; stage[q1-lo] = pk1 & 0x7FFFF;
      stage[q2-lo] = pk2 & 0x7FFFF; stage[q3-lo] = pk3 & 0x7FFFF;
    }
    for (; p < hi; p += 256){
      int pk = pairs[p];
      int q = atomicAdd(&cur[tkey(pk)], 1);
      stage[q-lo] = pk & 0x7FFFF;
    }
    __syncthreads();
    for (int s2=t; s2<cap; s2+=256) src[lo+s2] = stage[s2];
  } else {
    // fallback: direct scatter (correctness for oversized buckets)
    int p = lo + t;
    for (; p + 3*256 < hi; p += 4*256){
      int pk0=pairs[p], pk1=pairs[p+256], pk2=pairs[p+512], pk3=pairs[p+768];
      int q0 = atomicAdd(&cur[tkey(pk0)], 1);
      int q1 = atomicAdd(&cur[tkey(pk1)], 1);
      int q2 = atomicAdd(&cur[tkey(pk2)], 1);
      int q3 = atomicAdd(&cur[tkey(pk3)], 1);
      src[q0] = pk0 & 0x7FFFF; src[q1] = pk1 & 0x7FFFF;
      src[q2] = pk2 & 0x7FFFF; src[q3] = pk3 & 0x7FFFF;
    }
    for (; p < hi; p += 256){
      int pk = pairs[p];
      int q = atomicAdd(&cur[tkey(pk)], 1);
      src[q] = pk & 0x7FFFF;
    }
  }
}

// ---- lin-first: g = dinv * (x @ W0 + b0), row stride 16 ------------------
template<typename GT>
__global__ void k_lin_first(const void* __restrict__ x, const void* __restrict__ W,
                            const void* __restrict__ b, const int* __restrict__ flags,
                            const float* __restrict__ dinv,
                            GT* __restrict__ g, int n){
  __shared__ float Ws[4*EMB];
  __shared__ float bs[EMB];
  int t = threadIdx.x;
  int isbf = flags[1];
  if (t < 4*EMB) Ws[t] = ldf(W, t, isbf);
  if (t < EMB)   bs[t] = ldf(b, t, isbf);
  __syncthreads();
  int i = blockIdx.x*blockDim.x + t;
  if (i >= n) return;
  float xi[4];
  #pragma unroll
  for (int k=0;k<4;k++) xi[k] = ldf(x, (size_t)i*4+k, isbf);
  float d = dinv[i];
  float o[12];
  #pragma unroll
  for (int j=0;j<EMB;j++){
    float h = bs[j];
    #pragma unroll
    for (int k=0;k<4;k++) h = fmaf(xi[k], Ws[k*EMB+j], h);
    o[j] = d*h;
  }
  rowstore(g + (size_t)i*16, o);
}

// ---- lin-mid (fallback path) ---------------------------------------------
template<typename GT>
__global__ void k_lin_mid(const float* __restrict__ acc, const void* __restrict__ W,
                          const void* __restrict__ b, const int* __restrict__ flags,
                          const float* __restrict__ dinv,
                          GT* __restrict__ g, int n){
  __shared__ float Ws[EMB*EMB];
  __shared__ float bs[EMB];
  int t = threadIdx.x;
  int isbf = flags[1];
  if (t < EMB*EMB) Ws[t] = ldf(W, t, isbf);
  if (t < EMB)     bs[t] = ldf(b, t, isbf);
  __syncthreads();
  int i = blockIdx.x*blockDim.x + t;
  if (i >= n) return;
  float xi[EMB];
  size_t abase = (size_t)i*EMB;
  #pragma unroll
  for (int k=0;k<EMB;k++) xi[k] = tanhf(acc[abase+k]);
  float d = dinv[i];
  float o[12];
  #pragma unroll
  for (int j=0;j<EMB;j++){
    float h = bs[j];
    #pragma unroll
    for (int k=0;k<EMB;k++) h = fmaf(xi[k], Ws[k*EMB+j], h);
    o[j] = d*h;
  }
  rowstore(g + (size_t)i*16, o);
}

// ---- epilogue: self-loop + tanh (+MLP) + store ---------------------------
template<typename GT, int MODE>
__device__ __forceinline__ void finish_col(int c, int n, const float a[12],
                                           const GT* __restrict__ gin,
                                           const float* __restrict__ dinv,
                                           const float* Ws, const float* bs,
                                           void* __restrict__ outp){
  if (c >= n) return;
  float v[12];
  rowload(gin + (size_t)c*16, v);         // self-loop
  #pragma unroll
  for (int j=0;j<12;j++) v[j] += a[j];
  float d = dinv[c];
  if (MODE == 0){
    float h[12];
    #pragma unroll
    for (int k=0;k<12;k++) h[k] = tanhf(d*v[k]);
    float o[12];
    #pragma unroll
    for (int j=0;j<12;j++){
      float w = bs[j];
      #pragma unroll
      for (int k=0;k<12;k++) w = fmaf(h[k], Ws[k*EMB+j], w);
      o[j] = d*w;
    }
    rowstore((GT*)outp + (size_t)c*16, o);
  } else {
    float4* ap = (float4*)((float*)outp + (size_t)c*EMB);
    ap[0] = make_float4(tanhf(d*v[0]), tanhf(d*v[1]), tanhf(d*v[2]),  tanhf(d*v[3]));
    ap[1] = make_float4(tanhf(d*v[4]), tanhf(d*v[5]), tanhf(d*v[6]),  tanhf(d*v[7]));
    ap[2] = make_float4(tanhf(d*v[8]), tanhf(d*v[9]), tanhf(d*v[10]), tanhf(d*v[11]));
  }
}

// ---- XCD-rotated tile gather, pair-split (no barriers) -------------------
// Lane pair (2k,2k+1) owns one column; each tile segment is split by edge
// parity. Block = 128 cols -> grid 3125 (12 blocks/CU, waves cap 32/CU):
// 2.6x the outstanding loads of the 2-col/thread version (latency-bound fix).
// Tile visit order still rotates by blockIdx&7 (XCD L2 alignment).
// MODE 0: conv -> tanh -> @W+b -> *dinv -> gout (stride 16, GT)
// MODE 1: conv -> tanh -> acc (f32, stride 12)
template<typename GT, int MODE>
__global__ void __launch_bounds__(256)
k_gather_rot(const int* __restrict__ rs2, const int* __restrict__ src,
             const float* __restrict__ dinv, const GT* __restrict__ gin,
             const void* __restrict__ W, const void* __restrict__ b,
             const int* __restrict__ flags, void* __restrict__ outp,
             int n, int nt){
  __shared__ float Ws[EMB*EMB];
  __shared__ float bs[EMB];
  int t = threadIdx.x;
  if (MODE == 0){
    int isbf = flags[1];
    if (t < EMB*EMB) Ws[t] = ldf(W, t, isbf);
    if (t < EMB)     bs[t] = ldf(b, t, isbf);
    __syncthreads();
  }
  int par = t & 1;
  int c = blockIdx.x*128 + (t>>1);
  int q = (c < n) ? c : 0;
  int base = ((q>>BSHIFT)<<12) + (q & (BSPAN-1));
  float a[12];
  #pragma unroll
  for (int j=0;j<12;j++) a[j] = 0.f;
  int tau = (int)(blockIdx.x & 7) % nt;
  int i0 = base + (tau<<BSHIFT);
  int s = rs2[i0], e = rs2[i0+1];
  for (int k=0; k<nt; k++){
    int tn = tau+1; if (tn >= nt) tn = 0;
    int ps=0, pe=0;
    if (k+1 < nt){
      int ni = base + (tn<<BSHIFT);
      ps = rs2[ni]; pe = rs2[ni+1];
    }
    int p = s + par;
    for (; p+2 < e; p += 4){
      int r0 = src[p], r1 = src[p+2];
      float h0[12], h1[12];
      rowload(gin + (size_t)r0*16, h0);
      rowload(gin + (size_t)r1*16, h1);
      #pragma unroll
      for (int j=0;j<12;j++) a[j] += h0[j] + h1[j];
    }
    if (p < e){
      int r = src[p];
      float h[12];
      rowload(gin + (size_t)r*16, h);
      #pragma unroll
      for (int j=0;j<12;j++) a[j] += h[j];
    }
    s=ps; e=pe; tau=tn;
  }
  #pragma unroll
  for (int j=0;j<12;j++) a[j] += __shfl_xor(a[j], 1, 64);
  if (par == 0)
    finish_col<GT,MODE>(c, n, a, gin, dinv, Ws, bs, outp);
}

// ---- FALLBACK (small ws): atomic scatter path ----------------------------
__global__ void k_cnt_deg(const int* __restrict__ ei, const int* __restrict__ flags,
                          int* __restrict__ cnt, int e){
  int i = blockIdx.x*blockDim.x + threadIdx.x;
  if (i >= e) return;
  atomicAdd(&cnt[ld_col(ei, e, i, flags[0])], 1);
}
__global__ void k_dinv_from_cnt(const int* __restrict__ cnt, float* __restrict__ dinv, int n){
  int i = blockIdx.x*blockDim.x + threadIdx.x;
  if (i < n) dinv[i] = rsqrtf((float)(cnt[i] + 1));
}
__global__ void k_selfinit(const float* __restrict__ g, const float* __restrict__ dinv,
                           float* __restrict__ acc, int n){
  int i = blockIdx.x*blockDim.x + threadIdx.x;
  if (i >= n) return;
  float d = dinv[i];
  float h[12]; rowload(g + (size_t)i*16, h);
  #pragma unroll
  for (int j=0;j<EMB;j++) acc[(size_t)i*EMB+j] = d*h[j];
}
__global__ void k_scatter(const int* __restrict__ ei, const int* __restrict__ flags,
                          const float* __restrict__ dinv, const float* __restrict__ g,
                          float* __restrict__ acc, int e){
  int i = blockIdx.x*blockDim.x + threadIdx.x;
  if (i >= e) return;
  int w64 = flags[0];
  int r = ld_row(ei, e, i, w64);
  int c = ld_col(ei, e, i, w64);
  float w = dinv[c];
  float h[12];
  rowload(g + (size_t)r*16, h);
  float* ap = acc + (size_t)c*EMB;
  #pragma unroll
  for (int j=0;j<EMB;j++) atomicAdd(ap+j, w*h[j]);
}

// ---- pooling + output head ----------------------------------------------
template<int DOTANH>
__global__ void __launch_bounds__(256)
k_pool(const float* __restrict__ acc, const int* __restrict__ batch,
       const int* __restrict__ flags,
       const void* __restrict__ Wout, const void* __restrict__ bout,
       void* __restrict__ out, int n){
  int g = blockIdx.x;
  int w64  = flags[0];
  int isbf = flags[1];
  __shared__ int se[2];
  __shared__ float smax[4][EMB];
  __shared__ float ssum[4][EMB];
  __shared__ float hid[2*EMB];
  if (threadIdx.x == 0){
    int lo=0, hi=n;
    while (lo<hi){ int m=(lo+hi)>>1; if (ld_batch(batch,m,w64) < g) lo=m+1; else hi=m; }
    se[0]=lo;
    int lo2=lo; hi=n;
    while (lo2<hi){ int m=(lo2+hi)>>1; if (ld_batch(batch,m,w64) < g+1) lo2=m+1; else hi=m; }
    se[1]=lo2;
  }
  __syncthreads();
  int start=se[0], end=se[1];
  float lmax[EMB], lsum[EMB];
  #pragma unroll
  for (int j=0;j<EMB;j++){ lmax[j]=-3.0e38f; lsum[j]=0.f; }
  for (int i=start+(int)threadIdx.x; i<end; i+=blockDim.x){
    size_t base=(size_t)i*EMB;
    #pragma unroll
    for (int j=0;j<EMB;j++){
      float h = DOTANH ? tanhf(acc[base+j]) : acc[base+j];
      lmax[j] = fmaxf(lmax[j], h);
      lsum[j] += h;
    }
  }
  #pragma unroll
  for (int m=32;m>=1;m>>=1){
    #pragma unroll
    for (int j=0;j<EMB;j++){
      lmax[j] = fmaxf(lmax[j], __shfl_xor(lmax[j], m, 64));
      lsum[j] += __shfl_xor(lsum[j], m, 64);
    }
  }
  int wave = threadIdx.x>>6, lane = threadIdx.x&63;
  if (lane==0){
    #pragma unroll
    for (int j=0;j<EMB;j++){ smax[wave][j]=lmax[j]; ssum[wave][j]=lsum[j]; }
  }
  __syncthreads();
  int cnt = end-start;
  if (threadIdx.x < EMB){
    int j = threadIdx.x;
    float mx=smax[0][j], sm=ssum[0][j];
    #pragma unroll
    for (int w=1;w<4;w++){ mx=fmaxf(mx,smax[w][j]); sm+=ssum[w][j]; }
    if (cnt <= 0){ mx = 0.f; sm = 0.f; }
    float mean = sm / fmaxf((float)cnt, 1.0f);
    hid[j]     = mx;
    hid[EMB+j] = mean;
    stout(out, (size_t)NG*NCLS + (size_t)g*2*EMB + j,       mx,   isbf);
    stout(out, (size_t)NG*NCLS + (size_t)g*2*EMB + EMB + j, mean, isbf);
  }
  __syncthreads();
  if (threadIdx.x < NCLS){
    int c = threadIdx.x;
    float o = ldf(bout, c, isbf);
    #pragma unroll
    for (int k=0;k<2*EMB;k++) o = fmaf(hid[k], ldf(Wout, (size_t)k*NCLS+c, isbf), o);
    stout(out, (size_t)g*NCLS + c, o, isbf);
  }
}

__global__ void k_zero_out_noflags(void* __restrict__ out, int m){
  int i = blockIdx.x*blockDim.x + threadIdx.x;
  if (i < m) ((float*)out)[i] = 0.0f;
}

// ---- CSR build (shared) --------------------------------------------------
static void build_csr(const int* ei, const void* x, int* flags, int* bcnt, int* bbase,
                      int* bofs, float* dinv, int* src, int* pairs, int* rs2,
                      int N, int E, int NB, hipStream_t stream){
  const int TB = 256;
  const int gc = (E + CHUNK - 1) / CHUNK;
  const int NBK = NB * NKEY;
  k_detect      <<<1, 64, 0, stream>>>(ei, (const unsigned short*)x, flags);
  k_zero_i      <<<(NB+TB-1)/TB, TB, 0, stream>>>(bcnt, NB);
  k_bkt_count   <<<gc, TB, 0, stream>>>(ei, flags, bcnt, bofs, E, NB);
  k_bkt_scan_par<<<1, 1024, 0, stream>>>(bcnt, bbase, rs2, NB, NBK);
  k_colscan     <<<NB, TB, 0, stream>>>(bofs, bbase, NB, gc);
  k_bkt_place   <<<gc, TB, 0, stream>>>(ei, flags, bofs, pairs, E, NB);
  k_group       <<<NB, TB, 0, stream>>>(pairs, bbase, dinv, src, rs2, N);
}

static size_t alignup(size_t v){ return (v + 63) & ~(size_t)63; }
static size_t maxsz(size_t a, size_t b){ return a > b ? a : b; }

extern "C" void kernel_launch(void* const* d_in, const int* in_sizes, int n_in,
                              void* d_out, int out_size, void* d_ws, size_t ws_size,
                              hipStream_t stream) {
  const void* x     = d_in[0];
  const int*  ei    = (const int*)d_in[1];
  const int*  batch = (const int*)d_in[2];
  const void* W0 = d_in[3];  const void* b0 = d_in[4];
  const void* W1 = d_in[5];  const void* b1 = d_in[6];
  const void* W2 = d_in[7];  const void* b2 = d_in[8];
  const void* W3 = d_in[9];  const void* b3 = d_in[10];
  const void* Wout = d_in[11]; const void* bout = d_in[12];

  const int N = in_sizes[0] / 4;
  const int E = in_sizes[1] / 2;
  const int NB = (N + BSPAN - 1) >> BSHIFT;
  const int GC = (E + CHUNK - 1) / CHUNK;
  const int TB = 256;
  const int gn = (N + TB - 1) / TB;
  const int gr = (N + 127) / 128;     // pair-split rotated gather grid
  const int nt = (N + (1<<TSHIFT) - 1) >> TSHIFT;

  char* base = (char*)d_ws;

  size_t o_flags  = 0;
  size_t o_dinv   = alignup(o_flags + 64);
  size_t o_bcnt   = alignup(o_dinv + (size_t)N*4);
  size_t o_bbase  = alignup(o_bcnt + (size_t)NB*4);
  size_t o_bofs   = alignup(o_bbase + ((size_t)NB+1)*4);
  size_t o_rs2    = alignup(o_bofs + (size_t)GC*NB*4);
  size_t o_src    = alignup(o_rs2 + ((size_t)NB*NKEY + 1)*4);
  size_t o_buf    = alignup(o_src + (size_t)E*4);     // pairs aliases from here

  int* flags  = (int*)(base+o_flags);
  float* dinv = (float*)(base+o_dinv);
  int* bcnt   = (int*)(base+o_bcnt);
  int* bbase  = (int*)(base+o_bbase);
  int* bofs   = (int*)(base+o_bofs);
  int* rs2    = (int*)(base+o_rs2);
  int* src    = (int*)(base+o_src);
  int* pairs  = (int*)(base+o_buf);

  bool fast_ok = (N < (1<<19)) && (NB <= MAXNB) && (nt <= NTILE);

  // T1: rotated-tile gather, bf16 g double-buffered. acc aliases R0.
  {
    size_t szR0 = maxsz((size_t)N*16*2, (size_t)N*EMB*4);
    size_t o_gB = alignup(o_buf + szR0);
    size_t need = o_gB + (size_t)N*16*2;
    bool pairs_fit = (size_t)E*4 <= need - o_buf;
    if (fast_ok && pairs_fit && ws_size >= need){
      bf16*  gA  = (bf16*)(base+o_buf);
      bf16*  gB  = (bf16*)(base+o_gB);
      float* acc = (float*)(base+o_buf);
      build_csr(ei, x, flags, bcnt, bbase, bofs, dinv, src, pairs, rs2, N, E, NB, stream);
      k_lin_first<bf16><<<gn, TB, 0, stream>>>(x, W0, b0, flags, dinv, gA, N);
      k_gather_rot<bf16,0><<<gr, TB, 0, stream>>>(rs2, src, dinv, gA, W1, b1, flags, gB, N, nt);
      k_gather_rot<bf16,0><<<gr, TB, 0, stream>>>(rs2, src, dinv, gB, W2, b2, flags, gA, N, nt);
      k_gather_rot<bf16,0><<<gr, TB, 0, stream>>>(rs2, src, dinv, gA, W3, b3, flags, gB, N, nt);
      k_gather_rot<bf16,1><<<gr, TB, 0, stream>>>(rs2, src, dinv, gB, 0, 0, flags, acc, N, nt);
      k_pool<0><<<NG, 256, 0, stream>>>(acc, batch, flags, Wout, bout, d_out, N);
      return;
    }
  }

  // T2: rotated-tile gather, f32 g double-buffered. acc aliases gA.
  {
    size_t o_gA = o_buf;
    size_t o_gB = alignup(o_gA + (size_t)N*16*4);
    size_t need = o_gB + (size_t)N*16*4;
    bool pairs_fit = (size_t)E*4 <= need - o_buf;
    if (fast_ok && pairs_fit && ws_size >= need){
      float* gA  = (float*)(base+o_gA);
      float* gB  = (float*)(base+o_gB);
      float* acc = gA;
      build_csr(ei, x, flags, bcnt, bbase, bofs, dinv, src, pairs, rs2, N, E, NB, stream);
      k_lin_first<float><<<gn, TB, 0, stream>>>(x, W0, b0, flags, dinv, gA, N);
      k_gather_rot<float,0><<<gr, TB, 0, stream>>>(rs2, src, dinv, gA, W1, b1, flags, gB, N, nt);
      k_gather_rot<float,0><<<gr, TB, 0, stream>>>(rs2, src, dinv, gB, W2, b2, flags, gA, N, nt);
      k_gather_rot<float,0><<<gr, TB, 0, stream>>>(rs2, src, dinv, gA, W3, b3, flags, gB, N, nt);
      k_gather_rot<float,1><<<gr, TB, 0, stream>>>(rs2, src, dinv, gB, 0, 0, flags, acc, N, nt);
      k_pool<0><<<NG, 256, 0, stream>>>(acc, batch, flags, Wout, bout, d_out, N);
      return;
    }
  }

  // T4: atomic-scatter fallback
  {
    size_t f_cnt  = alignup(o_dinv + (size_t)N*4);
    size_t f_g    = alignup(f_cnt + (size_t)N*4);
    size_t f_acc  = alignup(f_g + (size_t)N*16*4);
    size_t f_end  = f_acc + (size_t)N*EMB*4;
    const int ge = (E + TB - 1) / TB;
    int* cnt = (int*)(base+f_cnt);

    if (ws_size >= f_end){
      float* g   = (float*)(base+f_g);
      float* acc = (float*)(base+f_acc);
      k_detect  <<<1, 64, 0, stream>>>(ei, (const unsigned short*)x, flags);
      k_zero_i  <<<gn, TB, 0, stream>>>(cnt, N);
      k_cnt_deg <<<ge, TB, 0, stream>>>(ei, flags, cnt, E);
      k_dinv_from_cnt<<<gn, TB, 0, stream>>>(cnt, dinv, N);
      k_lin_first<float><<<gn, TB, 0, stream>>>(x, W0, b0, flags, dinv, g, N);
      k_selfinit <<<gn, TB, 0, stream>>>(g, dinv, acc, N);
      k_scatter  <<<ge, TB, 0, stream>>>(ei, flags, dinv, g, acc, E);
      const void* Wl[3] = {W1,W2,W3};
      const void* bl[3] = {b1,b2,b3};
      for (int l=0;l<3;l++){
        k_lin_mid<float><<<gn, TB, 0, stream>>>(acc, Wl[l], bl[l], flags, dinv, g, N);
        k_selfinit<<<gn, TB, 0, stream>>>(g, dinv, acc, N);
        k_scatter <<<ge, TB, 0, stream>>>(ei, flags, dinv, g, acc, E);
      }
      k_pool<1><<<NG, 256, 0, stream>>>(acc, batch, flags, Wout, bout, d_out, N);
    } else {
      k_zero_out_noflags<<<(out_size+255)/256, 256, 0, stream>>>(d_out, out_size);
    }
  }
}